// Round 10
// baseline (143.234 us; speedup 1.0000x reference)
//
#include <hip/hip_runtime.h>
#include <math.h>

#define NN 64      // nodes per graph
#define HH 128     // hidden channels
#define NBB 8      // bessel basis
#define TT 32      // time embedding dim
#define BB 64      // batch
#define NROW (BB * NN)        // 4096 total rows
#define PLANE ((size_t)NROW * HH)   // 524288
#define WR1OFF (8 * 16384)    // Wr1 B-frag slabs in Wpack (2 x 4096)

typedef __attribute__((ext_vector_type(8))) short short8;
typedef __attribute__((ext_vector_type(4))) float f32x4;
typedef __attribute__((ext_vector_type(2))) unsigned int u32x2;

__device__ __forceinline__ float silu_f(float x) {
  return x * __builtin_amdgcn_rcpf(1.0f + __expf(-x));
}

__device__ __forceinline__ unsigned short bf1(float x) {
  __bf16 h = (__bf16)x;
  return *(unsigned short*)&h;
}
__device__ __forceinline__ unsigned bf2(float lo, float hi) {
  return (unsigned)bf1(lo) | ((unsigned)bf1(hi) << 16);
}

// 8-row MFMA GEMM tile: A rows 8..15 zero. C map: row=quad*4+reg (<8), col=w*32+nt*16+nlo.
__device__ __forceinline__ void gemm8(
    const unsigned short (*sA)[136], const unsigned short* __restrict__ Bp,
    int w, int nlo, int quad, f32x4 C[2]) {
  const short8 z8 = {0, 0, 0, 0, 0, 0, 0, 0};
  short8 afr[4];
#pragma unroll
  for (int kt = 0; kt < 4; ++kt)
    afr[kt] = (nlo < 8) ? *(const short8*)&sA[nlo][kt * 32 + quad * 8] : z8;
#pragma unroll
  for (int nt = 0; nt < 2; ++nt)
#pragma unroll
    for (int kt = 0; kt < 4; ++kt) {
      short8 bfr = *(const short8*)&Bp[((kt * 128 + w * 32 + nt * 16 + nlo) * 4 + quad) * 8];
      C[nt] = __builtin_amdgcn_mfma_f32_16x16x32_bf16(afr[kt], bfr, C[nt], 0, 0, 0);
    }
}

// Grid 256. Pack all weights -> bf16 MFMA-B-frag order; blocks<64 init h. (R2-exact)
__global__ __launch_bounds__(256) void k_init(
    const float* __restrict__ emb, const int* __restrict__ z,
    const float* __restrict__ gf, const float* __restrict__ Wt,
    const float* __restrict__ Wr1, const float* __restrict__ Wr2,
    const float* __restrict__ Wupd, const float* __restrict__ Wmix,
    const float* __restrict__ Wg1, const float* __restrict__ Wg2,
    float* __restrict__ h, unsigned short* __restrict__ Wpack) {
  __shared__ float tvec[HH];
  __shared__ int sz[NN];
  int b4 = blockIdx.x, tid = threadIdx.x;
  {
    int p2 = b4 * 256 + tid;
    int p = p2 * 2;
    int m = p >> 14;
    int j = p & 7;
    int q = (p >> 3) & 3;
    int n = (p >> 5) & 127;
    int kt = (p >> 12) & 3;
    int k = kt * 32 + q * 8 + j;
    const float* src;
    int base;
    if (m < 2) { src = Wr2; base = m * 16384; }
    else if (m < 4) { src = Wupd; base = (m - 2) * 16384; }
    else if (m < 6) { src = Wmix; base = (m - 4) * 16384; }
    else if (m == 6) { src = Wg1; base = 0; }
    else { src = Wg2; base = 0; }
    float v0 = src[base + k * 128 + n];
    float v1 = src[base + (k + 1) * 128 + n];
    *(unsigned*)&Wpack[p] = bf2(v0, v1);
  }
  if (tid < 32) {
    int e = b4 * 32 + tid;
    int l = e >> 12, p = e & 4095;
    int n = p >> 5, q = (p >> 3) & 3, j = p & 7;
    float val = (q == 0) ? Wr1[l * NBB * HH + j * HH + n] : 0.f;
    Wpack[WR1OFF + l * 4096 + p] = bf1(val);
  }
  if (b4 < 64) {
    int b = b4;
    if (tid < NN) sz[tid] = z[b * NN + tid];
    if (tid < HH) {
      float acc = 0.f;
#pragma unroll
      for (int k = 0; k < TT; ++k) acc += gf[b * TT + k] * Wt[k * HH + tid];
      tvec[tid] = acc;
    }
    __syncthreads();
    for (int i = tid; i < NN * HH; i += 256) {
      int n = i >> 7, c = i & 127;
      h[(size_t)b * NN * HH + i] = emb[sz[n] * HH + c] + tvec[c];
    }
  }
}

// Layer 0. Grid BB*8 = 512 (fully co-resident): block = (b, u8), 8 receivers as
// two 4-receiver units; hbv prefetch + frag hoists amortize over 8 receivers.
__global__ __launch_bounds__(256) void k_layer0(
    const float* __restrict__ pos, const float* __restrict__ hA,
    unsigned short* __restrict__ apout, const unsigned short* __restrict__ Wpack) {
  __shared__ __align__(16) unsigned short sh_S[NN][136];     // 17408 B
  __shared__ __align__(16) unsigned short sh_M0T[4][32][72]; // 18432 B
  __shared__ __align__(16) unsigned short sh_rbh[4][NN][8];  // 4096 B
  __shared__ __align__(16) unsigned short sh_ub[4][4][NN];   // 2048 B

  int blk = blockIdx.x;
  int b = blk >> 3, u8 = blk & 7;
  int tid = threadIdx.x;
  int w = tid >> 6, lane = tid & 63;
  int nlo = lane & 15, quad = lane >> 4;
  const short8 zero8 = {0, 0, 0, 0, 0, 0, 0, 0};

  f32x4 hbv[4][2];
#pragma unroll
  for (int mt = 0; mt < 4; ++mt)
#pragma unroll
    for (int nt = 0; nt < 2; ++nt)
#pragma unroll
      for (int reg = 0; reg < 4; ++reg)
        hbv[mt][nt][reg] =
            hA[((size_t)b * NN + mt * 16 + quad * 4 + reg) * HH + w * 32 + nt * 16 + nlo];

  const unsigned short* Wr1p = Wpack + WR1OFF;
  short8 bw[2];
#pragma unroll
  for (int nt = 0; nt < 2; ++nt)
    bw[nt] = *(const short8*)&Wr1p[((w * 32 + nt * 16 + nlo) * 4 + quad) * 8];
  const unsigned short* Bbase = Wpack;
  short8 bfr[4][2];
#pragma unroll
  for (int kt = 0; kt < 4; ++kt)
#pragma unroll
    for (int nt = 0; nt < 2; ++nt)
      bfr[kt][nt] = *(const short8*)&Bbase[((kt * 128 + w * 32 + nt * 16 + nlo) * 4 + quad) * 8];

  for (int unit = 0; unit < 2; ++unit) {
    int r0 = u8 * 8 + unit * 4;

    // ---- Stage A: 4 receivers of this unit ----
    {
      int s = tid & 63;
      int ri4 = tid >> 6;
      int r = r0 + ri4;
      const float* pb = pos + b * NN * 3;
      float dx = pb[r * 3 + 0] - pb[s * 3 + 0];
      float dy = pb[r * 3 + 1] - pb[s * 3 + 1];
      float dz = pb[r * 3 + 2] - pb[s * 3 + 2];
      float rr = sqrtf(dx * dx + dy * dy + dz * dz + 1e-12f);
      float inv = __builtin_amdgcn_rcpf(rr);
      const float invAvg = 1.0f / 63.0f;
      float ia = inv * invAvg;
      sh_ub[ri4][0][s] = bf1(invAvg);
      sh_ub[ri4][1][s] = bf1(dx * ia);
      sh_ub[ri4][2][s] = bf1(dy * ia);
      sh_ub[ri4][3][s] = bf1(dz * ia);
      const float PI_OVER_5 = 0.628318530717958647692f;
      float fc = (s != r && rr < 5.0f) ? 0.5f * (__cosf(PI_OVER_5 * rr) + 1.0f) : 0.0f;
      float base = PI_OVER_5 * rr;
      float sc = inv * fc;
#pragma unroll
      for (int k0 = 0; k0 < 8; k0 += 4) {
        float v0 = __sinf((float)(k0 + 1) * base) * sc;
        float v1 = __sinf((float)(k0 + 2) * base) * sc;
        float v2 = __sinf((float)(k0 + 3) * base) * sc;
        float v3 = __sinf((float)(k0 + 4) * base) * sc;
        *(unsigned*)&sh_rbh[ri4][s][k0]     = bf2(v0, v1);
        *(unsigned*)&sh_rbh[ri4][s][k0 + 2] = bf2(v2, v3);
      }
    }
    __syncthreads();

#pragma unroll
    for (int rsel = 0; rsel < 4; ++rsel) {
      // ---- Stage B ----
#pragma unroll
      for (int mtp = 0; mtp < 2; ++mtp) {
        f32x4 Cs[2][2];
#pragma unroll
        for (int mi = 0; mi < 2; ++mi)
#pragma unroll
          for (int nt = 0; nt < 2; ++nt) Cs[mi][nt] = (f32x4){0.f, 0.f, 0.f, 0.f};
#pragma unroll
        for (int mi = 0; mi < 2; ++mi) {
          int mt = mtp * 2 + mi;
          short8 afr = (quad == 0) ? *(const short8*)&sh_rbh[rsel][mt * 16 + nlo][0] : zero8;
#pragma unroll
          for (int nt = 0; nt < 2; ++nt)
            Cs[mi][nt] = __builtin_amdgcn_mfma_f32_16x16x32_bf16(afr, bw[nt], Cs[mi][nt], 0, 0, 0);
        }
#pragma unroll
        for (int mi = 0; mi < 2; ++mi)
#pragma unroll
          for (int nt = 0; nt < 2; ++nt)
#pragma unroll
            for (int reg = 0; reg < 4; ++reg) {
              int s = (mtp * 2 + mi) * 16 + quad * 4 + reg;
              int c = w * 32 + nt * 16 + nlo;
              sh_S[s][c] = bf1(silu_f(Cs[mi][nt][reg]));
            }
      }
      __syncthreads();

      // ---- Main GEMM + M0T ----
#pragma unroll
      for (int mt = 0; mt < 4; ++mt) {
        short8 afr[4];
        int s_a = mt * 16 + nlo;
#pragma unroll
        for (int kt = 0; kt < 4; ++kt)
          afr[kt] = *(const short8*)&sh_S[s_a][kt * 32 + quad * 8];
#pragma unroll
        for (int nt = 0; nt < 2; ++nt) {
          f32x4 C = {0.f, 0.f, 0.f, 0.f};
#pragma unroll
          for (int kt = 0; kt < 4; ++kt)
            C = __builtin_amdgcn_mfma_f32_16x16x32_bf16(afr[kt], bfr[kt][nt], C, 0, 0, 0);
          f32x4 m0 = C * hbv[mt][nt];
          u32x2 pk;
          pk.x = bf2(m0[0], m0[1]);
          pk.y = bf2(m0[2], m0[3]);
          *(u32x2*)&sh_M0T[w][nt * 16 + nlo][mt * 16 + quad * 4] = pk;
        }
      }
      // ---- U-GEMM -> global planes 0-3 ----
      {
        short8 au[2];
#pragma unroll
        for (int kt = 0; kt < 2; ++kt)
          au[kt] = (nlo < 4) ? *(const short8*)&sh_ub[rsel][nlo][kt * 32 + quad * 8] : zero8;
        f32x4 Cu[2] = {{0, 0, 0, 0}, {0, 0, 0, 0}};
#pragma unroll
        for (int nt = 0; nt < 2; ++nt)
#pragma unroll
          for (int kt = 0; kt < 2; ++kt) {
            short8 bm = *(const short8*)&sh_M0T[w][nt * 16 + nlo][kt * 32 + quad * 8];
            Cu[nt] = __builtin_amdgcn_mfma_f32_16x16x32_bf16(au[kt], bm, Cu[nt], 0, 0, 0);
          }
        if (quad == 0) {
#pragma unroll
          for (int nt = 0; nt < 2; ++nt) {
            size_t base = (size_t)(b * NN + r0 + rsel) * HH + w * 32 + nt * 16 + nlo;
#pragma unroll
            for (int reg = 0; reg < 4; ++reg)
              apout[reg * PLANE + base] = bf1(Cu[nt][reg]);
          }
        }
      }
      if (!(unit == 1 && rsel == 3)) __syncthreads();
    }
  }
}

// Fused layer-1 + update/readout. Grid 512: block blk = (b = blk>>3, u8 = blk&7)
// computes receivers [u8*8, u8*8+8) = rows [blk*8, blk*8+8), then updates/reads
// out those rows. Planes 4-7 stay in LDS (sh_a47). Update's Ch = hbv restricted
// to the block's 8 rows (hbv already includes h + a0l0@Wupd0 from the prologue)
// -- no hA reload, no Wupd0 gemm8, no plane-0 staging in the update phase.
__global__ __launch_bounds__(256) void k_fused(
    const float* __restrict__ pos, const float* __restrict__ hA,
    unsigned short* __restrict__ apbf, const unsigned short* __restrict__ Wpack,
    const float* __restrict__ fs, float* __restrict__ out) {
  __shared__ __align__(16) unsigned char smem[50688];
  unsigned short (*sh_S)[136]      = (unsigned short (*)[136])smem;               // 17408 B
  unsigned short (*sh_M0T)[32][72] = (unsigned short (*)[32][72])(smem + 17408);  // 18432 B
  unsigned short (*sh_rbh)[NN][8]  = (unsigned short (*)[NN][8])(smem + 35840);   // 4096 B
  unsigned short (*sh_ub)[4][NN]   = (unsigned short (*)[4][NN])(smem + 39936);   // 2048 B
  unsigned short (*sh_a47)[8][136] = (unsigned short (*)[8][136])(smem + 41984);  // 8704 B

  int blk = blockIdx.x;
  int b = blk >> 3, u8 = blk & 7;
  int tid = threadIdx.x;
  int w = tid >> 6, lane = tid & 63;
  int nlo = lane & 15, quad = lane >> 4;
  const short8 zero8 = {0, 0, 0, 0, 0, 0, 0, 0};

  // ---- hbv: graph h in C-reg layout ----
  f32x4 hbv[4][2];
#pragma unroll
  for (int mt = 0; mt < 4; ++mt)
#pragma unroll
    for (int nt = 0; nt < 2; ++nt)
#pragma unroll
      for (int reg = 0; reg < 4; ++reg)
        hbv[mt][nt][reg] =
            hA[((size_t)b * NN + mt * 16 + quad * 4 + reg) * HH + w * 32 + nt * 16 + nlo];

  // ---- stage a0_l0 (prior launch) and apply hbv += a0_l0 @ Wupd0 ----
  for (int i = tid; i < NN * 64; i += 256) {
    int s = i >> 6, c2 = (i & 63) * 2;
    *(unsigned*)&sh_S[s][c2] =
        *(const unsigned*)&apbf[((size_t)b * NN + s) * HH + c2];
  }
  __syncthreads();
  {
    const unsigned short* Bu = Wpack + 2 * 16384;
#pragma unroll
    for (int mt = 0; mt < 4; ++mt) {
      short8 afr[4];
#pragma unroll
      for (int kt = 0; kt < 4; ++kt)
        afr[kt] = *(const short8*)&sh_S[mt * 16 + nlo][kt * 32 + quad * 8];
#pragma unroll
      for (int nt = 0; nt < 2; ++nt)
#pragma unroll
        for (int kt = 0; kt < 4; ++kt) {
          short8 bfr2 = *(const short8*)&Bu[((kt * 128 + w * 32 + nt * 16 + nlo) * 4 + quad) * 8];
          hbv[mt][nt] = __builtin_amdgcn_mfma_f32_16x16x32_bf16(afr[kt], bfr2, hbv[mt][nt], 0, 0, 0);
        }
    }
  }
  __syncthreads();   // sh_S reads done before Stage B overwrites

  // ---- layer-1 fragment hoists ----
  const unsigned short* Wr1p = Wpack + WR1OFF + 4096;
  short8 bw[2];
#pragma unroll
  for (int nt = 0; nt < 2; ++nt)
    bw[nt] = *(const short8*)&Wr1p[((w * 32 + nt * 16 + nlo) * 4 + quad) * 8];
  const unsigned short* Bbase = Wpack + 16384;
  short8 bfr[4][2];
#pragma unroll
  for (int kt = 0; kt < 4; ++kt)
#pragma unroll
    for (int nt = 0; nt < 2; ++nt)
      bfr[kt][nt] = *(const short8*)&Bbase[((kt * 128 + w * 32 + nt * 16 + nlo) * 4 + quad) * 8];

  for (int unit = 0; unit < 2; ++unit) {
    int r0 = u8 * 8 + unit * 4;

    // ---- Stage A: 4 receivers of this unit ----
    {
      int s = tid & 63;
      int ri4 = tid >> 6;
      int r = r0 + ri4;
      const float* pb = pos + b * NN * 3;
      float dx = pb[r * 3 + 0] - pb[s * 3 + 0];
      float dy = pb[r * 3 + 1] - pb[s * 3 + 1];
      float dz = pb[r * 3 + 2] - pb[s * 3 + 2];
      float rr = sqrtf(dx * dx + dy * dy + dz * dz + 1e-12f);
      float inv = __builtin_amdgcn_rcpf(rr);
      const float invAvg = 1.0f / 63.0f;
      float ia = inv * invAvg;
      sh_ub[ri4][0][s] = bf1(invAvg);
      sh_ub[ri4][1][s] = bf1(dx * ia);
      sh_ub[ri4][2][s] = bf1(dy * ia);
      sh_ub[ri4][3][s] = bf1(dz * ia);
      const float PI_OVER_5 = 0.628318530717958647692f;
      float fc = (s != r && rr < 5.0f) ? 0.5f * (__cosf(PI_OVER_5 * rr) + 1.0f) : 0.0f;
      float base = PI_OVER_5 * rr;
      float sc = inv * fc;
#pragma unroll
      for (int k0 = 0; k0 < 8; k0 += 4) {
        float v0 = __sinf((float)(k0 + 1) * base) * sc;
        float v1 = __sinf((float)(k0 + 2) * base) * sc;
        float v2 = __sinf((float)(k0 + 3) * base) * sc;
        float v3 = __sinf((float)(k0 + 4) * base) * sc;
        *(unsigned*)&sh_rbh[ri4][s][k0]     = bf2(v0, v1);
        *(unsigned*)&sh_rbh[ri4][s][k0 + 2] = bf2(v2, v3);
      }
    }
    __syncthreads();

#pragma unroll
    for (int rsel = 0; rsel < 4; ++rsel) {
      int lr = unit * 4 + rsel;   // local row 0..7
      // ---- Stage B ----
#pragma unroll
      for (int mtp = 0; mtp < 2; ++mtp) {
        f32x4 Cs[2][2];
#pragma unroll
        for (int mi = 0; mi < 2; ++mi)
#pragma unroll
          for (int nt = 0; nt < 2; ++nt) Cs[mi][nt] = (f32x4){0.f, 0.f, 0.f, 0.f};
#pragma unroll
        for (int mi = 0; mi < 2; ++mi) {
          int mt = mtp * 2 + mi;
          short8 afr = (quad == 0) ? *(const short8*)&sh_rbh[rsel][mt * 16 + nlo][0] : zero8;
#pragma unroll
          for (int nt = 0; nt < 2; ++nt)
            Cs[mi][nt] = __builtin_amdgcn_mfma_f32_16x16x32_bf16(afr, bw[nt], Cs[mi][nt], 0, 0, 0);
        }
#pragma unroll
        for (int mi = 0; mi < 2; ++mi)
#pragma unroll
          for (int nt = 0; nt < 2; ++nt)
#pragma unroll
            for (int reg = 0; reg < 4; ++reg) {
              int s = (mtp * 2 + mi) * 16 + quad * 4 + reg;
              int c = w * 32 + nt * 16 + nlo;
              sh_S[s][c] = bf1(silu_f(Cs[mi][nt][reg]));
            }
      }
      __syncthreads();

      // ---- Main GEMM + M0T ----
#pragma unroll
      for (int mt = 0; mt < 4; ++mt) {
        short8 afr[4];
        int s_a = mt * 16 + nlo;
#pragma unroll
        for (int kt = 0; kt < 4; ++kt)
          afr[kt] = *(const short8*)&sh_S[s_a][kt * 32 + quad * 8];
#pragma unroll
        for (int nt = 0; nt < 2; ++nt) {
          f32x4 C = {0.f, 0.f, 0.f, 0.f};
#pragma unroll
          for (int kt = 0; kt < 4; ++kt)
            C = __builtin_amdgcn_mfma_f32_16x16x32_bf16(afr[kt], bfr[kt][nt], C, 0, 0, 0);
          f32x4 m0 = C * hbv[mt][nt];
          u32x2 pk;
          pk.x = bf2(m0[0], m0[1]);
          pk.y = bf2(m0[2], m0[3]);
          *(u32x2*)&sh_M0T[w][nt * 16 + nlo][mt * 16 + quad * 4] = pk;
        }
      }
      // ---- U-GEMM -> sh_a47 (LDS only, no global) ----
      {
        short8 au[2];
#pragma unroll
        for (int kt = 0; kt < 2; ++kt)
          au[kt] = (nlo < 4) ? *(const short8*)&sh_ub[rsel][nlo][kt * 32 + quad * 8] : zero8;
        f32x4 Cu[2] = {{0, 0, 0, 0}, {0, 0, 0, 0}};
#pragma unroll
        for (int nt = 0; nt < 2; ++nt)
#pragma unroll
          for (int kt = 0; kt < 2; ++kt) {
            short8 bm = *(const short8*)&sh_M0T[w][nt * 16 + nlo][kt * 32 + quad * 8];
            Cu[nt] = __builtin_amdgcn_mfma_f32_16x16x32_bf16(au[kt], bm, Cu[nt], 0, 0, 0);
          }
        if (quad == 0) {
#pragma unroll
          for (int nt = 0; nt < 2; ++nt) {
            int c = w * 32 + nt * 16 + nlo;
#pragma unroll
            for (int reg = 0; reg < 4; ++reg)
              sh_a47[reg][lr][c] = bf1(Cu[nt][reg]);
          }
        }
      }
      __syncthreads();   // sh_S/rbh/ub safe to overwrite; a47 visible later
    }
  }

  // ---- update + readout for rows [blk*8, blk*8+8) ----
  {
    unsigned short (*sh_a03)[8][136] = (unsigned short (*)[8][136])smem;          // planes 1-3
    unsigned short (*sh_h)[136]      = (unsigned short (*)[136])(smem + 8704);    // 2176 B
    float (*red)[8][3]               = (float (*)[8][3])(smem + 8704 + 2176);     // 384 B
    int row0 = blk * 8;
    for (int i = tid; i < 3 * 8 * 64; i += 256) {
      int p = i >> 9, rr = (i >> 6) & 7, c2 = (i & 63) * 2;
      *(unsigned*)&sh_a03[p + 1][rr][c2] =
          *(const unsigned*)&apbf[(p + 1) * PLANE + (size_t)(row0 + rr) * HH + c2];
    }
    // Ch from hbv: rows u8*8+quad*4+reg live in hbv[u8>>1], quads 0-1 (even u8)
    // or quads 2-3 (odd u8; fetch via lane^32 shuffle). Unrolled select avoids
    // runtime-indexed vector array (scratch hazard).
    f32x4 hsel[2];
#pragma unroll
    for (int mt = 0; mt < 4; ++mt)
      if (mt == (u8 >> 1)) { hsel[0] = hbv[mt][0]; hsel[1] = hbv[mt][1]; }
    f32x4 Ch[2];
#pragma unroll
    for (int nt = 0; nt < 2; ++nt)
#pragma unroll
      for (int reg = 0; reg < 4; ++reg) {
        float own = hsel[nt][reg];
        float swp = __shfl(own, lane ^ 32);
        Ch[nt][reg] = (quad < 2) ? ((u8 & 1) ? swp : own) : 0.f;
      }
    __syncthreads();
    gemm8(sh_a47[0], Wpack + 3 * 16384, w, nlo, quad, Ch);   // + a0l1@Wupd1
    f32x4 Cx[2] = {{0,0,0,0},{0,0,0,0}};
    f32x4 Cy[2] = {{0,0,0,0},{0,0,0,0}};
    f32x4 Cz[2] = {{0,0,0,0},{0,0,0,0}};
    gemm8(sh_a03[1], Wpack + 4 * 16384, w, nlo, quad, Cx);
    gemm8(sh_a47[1], Wpack + 5 * 16384, w, nlo, quad, Cx);
    gemm8(sh_a03[2], Wpack + 4 * 16384, w, nlo, quad, Cy);
    gemm8(sh_a47[2], Wpack + 5 * 16384, w, nlo, quad, Cy);
    gemm8(sh_a03[3], Wpack + 4 * 16384, w, nlo, quad, Cz);
    gemm8(sh_a47[3], Wpack + 5 * 16384, w, nlo, quad, Cz);
    if (quad < 2) {
#pragma unroll
      for (int nt = 0; nt < 2; ++nt)
#pragma unroll
        for (int reg = 0; reg < 4; ++reg)
          sh_h[quad * 4 + reg][w * 32 + nt * 16 + nlo] = bf1(Ch[nt][reg]);
    }
    __syncthreads();   // sh_h ready; sh_a03[0] region free (never staged)
    unsigned short (*sh_q)[136] = sh_a03[0];
    f32x4 Cq[2] = {{0,0,0,0},{0,0,0,0}};
    gemm8(sh_h, Wpack + 6 * 16384, w, nlo, quad, Cq);
    if (quad < 2) {
#pragma unroll
      for (int nt = 0; nt < 2; ++nt)
#pragma unroll
        for (int reg = 0; reg < 4; ++reg)
          sh_q[quad * 4 + reg][w * 32 + nt * 16 + nlo] = bf1(silu_f(Cq[nt][reg]));
    }
    __syncthreads();
    f32x4 Cg[2] = {{0,0,0,0},{0,0,0,0}};
    gemm8(sh_q, Wpack + 7 * 16384, w, nlo, quad, Cg);
    float pr[3][4];
#pragma unroll
    for (int d = 0; d < 3; ++d)
#pragma unroll
      for (int reg = 0; reg < 4; ++reg) pr[d][reg] = 0.f;
#pragma unroll
    for (int nt = 0; nt < 2; ++nt)
#pragma unroll
      for (int reg = 0; reg < 4; ++reg) {
        float gv = Cg[nt][reg];
        pr[0][reg] += gv * Cx[nt][reg];
        pr[1][reg] += gv * Cy[nt][reg];
        pr[2][reg] += gv * Cz[nt][reg];
      }
#pragma unroll
    for (int off = 1; off < 16; off <<= 1)
#pragma unroll
      for (int d = 0; d < 3; ++d)
#pragma unroll
        for (int reg = 0; reg < 4; ++reg)
          pr[d][reg] += __shfl_xor(pr[d][reg], off);
    if (nlo == 0 && quad < 2) {
#pragma unroll
      for (int d = 0; d < 3; ++d)
#pragma unroll
        for (int reg = 0; reg < 4; ++reg)
          red[w][quad * 4 + reg][d] = pr[d][reg];
    }
    __syncthreads();
    if (tid < 24) {
      int row = tid / 3, d = tid % 3;
      float s = red[0][row][d] + red[1][row][d] + red[2][row][d] + red[3][row][d];
      out[(size_t)(row0 + row) * 3 + d] = s * fs[0];
    }
  }
}

extern "C" void kernel_launch(void* const* d_in, const int* in_sizes, int n_in,
                              void* d_out, int out_size, void* d_ws, size_t ws_size,
                              hipStream_t stream) {
  const float* pos  = (const float*)d_in[0];
  const int*   z    = (const int*)d_in[1];
  const float* gf   = (const float*)d_in[2];
  const float* emb  = (const float*)d_in[3];
  const float* Wt   = (const float*)d_in[4];
  const float* Wr1  = (const float*)d_in[5];
  const float* Wr2  = (const float*)d_in[6];
  const float* Wupd = (const float*)d_in[7];
  const float* Wmix = (const float*)d_in[8];
  const float* Wg1  = (const float*)d_in[9];
  const float* Wg2  = (const float*)d_in[10];
  const float* fs   = (const float*)d_in[11];
  float* out = (float*)d_out;

  float* ws = (float*)d_ws;
  float* hA = ws;                                         // 2 MB
  unsigned short* apbf = (unsigned short*)(ws + PLANE);   // bf16 planes (0-3 used)
  unsigned short* Wpack = (unsigned short*)(ws + 5 * PLANE);  // 272 KB

  k_init<<<dim3(256), dim3(256), 0, stream>>>(emb, z, gf, Wt, Wr1, Wr2, Wupd,
                                              Wmix, Wg1, Wg2, hA, Wpack);
  k_layer0<<<dim3(BB * 8), dim3(256), 0, stream>>>(pos, hA, apbf, Wpack);
  k_fused<<<dim3(512), dim3(256), 0, stream>>>(pos, hA, apbf, Wpack, fs, out);
}

// Round 11
// 140.793 us; speedup vs baseline: 1.0173x; 1.0173x over previous
//
#include <hip/hip_runtime.h>
#include <math.h>

#define NN 64      // nodes per graph
#define HH 128     // hidden channels
#define NBB 8      // bessel basis
#define TT 32      // time embedding dim
#define BB 64      // batch
#define NROW (BB * NN)        // 4096 total rows
#define PLANE ((size_t)NROW * HH)   // 524288
#define WR1OFF (8 * 16384)    // Wr1 B-frag slabs in Wpack (2 x 4096)

typedef __attribute__((ext_vector_type(8))) short short8;
typedef __attribute__((ext_vector_type(4))) float f32x4;
typedef __attribute__((ext_vector_type(2))) unsigned int u32x2;

__device__ __forceinline__ float silu_f(float x) {
  return x * __builtin_amdgcn_rcpf(1.0f + __expf(-x));
}

__device__ __forceinline__ unsigned short bf1(float x) {
  __bf16 h = (__bf16)x;
  return *(unsigned short*)&h;
}
__device__ __forceinline__ unsigned bf2(float lo, float hi) {
  return (unsigned)bf1(lo) | ((unsigned)bf1(hi) << 16);
}

// 8-row MFMA GEMM tile: A rows 8..15 zero. C map: row=quad*4+reg (<8), col=w*32+nt*16+nlo.
__device__ __forceinline__ void gemm8(
    const unsigned short (*sA)[136], const unsigned short* __restrict__ Bp,
    int w, int nlo, int quad, f32x4 C[2]) {
  const short8 z8 = {0, 0, 0, 0, 0, 0, 0, 0};
  short8 afr[4];
#pragma unroll
  for (int kt = 0; kt < 4; ++kt)
    afr[kt] = (nlo < 8) ? *(const short8*)&sA[nlo][kt * 32 + quad * 8] : z8;
#pragma unroll
  for (int nt = 0; nt < 2; ++nt)
#pragma unroll
    for (int kt = 0; kt < 4; ++kt) {
      short8 bfr = *(const short8*)&Bp[((kt * 128 + w * 32 + nt * 16 + nlo) * 4 + quad) * 8];
      C[nt] = __builtin_amdgcn_mfma_f32_16x16x32_bf16(afr[kt], bfr, C[nt], 0, 0, 0);
    }
}

// Grid 256. Pack all weights -> bf16 MFMA-B-frag order; blocks<64 init h. (R2-exact)
__global__ __launch_bounds__(256) void k_init(
    const float* __restrict__ emb, const int* __restrict__ z,
    const float* __restrict__ gf, const float* __restrict__ Wt,
    const float* __restrict__ Wr1, const float* __restrict__ Wr2,
    const float* __restrict__ Wupd, const float* __restrict__ Wmix,
    const float* __restrict__ Wg1, const float* __restrict__ Wg2,
    float* __restrict__ h, unsigned short* __restrict__ Wpack) {
  __shared__ float tvec[HH];
  __shared__ int sz[NN];
  int b4 = blockIdx.x, tid = threadIdx.x;
  {
    int p2 = b4 * 256 + tid;
    int p = p2 * 2;
    int m = p >> 14;
    int j = p & 7;
    int q = (p >> 3) & 3;
    int n = (p >> 5) & 127;
    int kt = (p >> 12) & 3;
    int k = kt * 32 + q * 8 + j;
    const float* src;
    int base;
    if (m < 2) { src = Wr2; base = m * 16384; }
    else if (m < 4) { src = Wupd; base = (m - 2) * 16384; }
    else if (m < 6) { src = Wmix; base = (m - 4) * 16384; }
    else if (m == 6) { src = Wg1; base = 0; }
    else { src = Wg2; base = 0; }
    float v0 = src[base + k * 128 + n];
    float v1 = src[base + (k + 1) * 128 + n];
    *(unsigned*)&Wpack[p] = bf2(v0, v1);
  }
  if (tid < 32) {
    int e = b4 * 32 + tid;
    int l = e >> 12, p = e & 4095;
    int n = p >> 5, q = (p >> 3) & 3, j = p & 7;
    float val = (q == 0) ? Wr1[l * NBB * HH + j * HH + n] : 0.f;
    Wpack[WR1OFF + l * 4096 + p] = bf1(val);
  }
  if (b4 < 64) {
    int b = b4;
    if (tid < NN) sz[tid] = z[b * NN + tid];
    if (tid < HH) {
      float acc = 0.f;
#pragma unroll
      for (int k = 0; k < TT; ++k) acc += gf[b * TT + k] * Wt[k * HH + tid];
      tvec[tid] = acc;
    }
    __syncthreads();
    for (int i = tid; i < NN * HH; i += 256) {
      int n = i >> 7, c = i & 127;
      h[(size_t)b * NN * HH + i] = emb[sz[n] * HH + c] + tvec[c];
    }
  }
}

// Layer 0 (R9-exact). Grid BB*16 = 1024, 4 receivers/block: 41984 B LDS -> 3
// blocks/CU = 12 waves/CU resident (grid-512 variant capped at 8 waves/CU and
// regressed in R10). Single Stage-A phase covers all 4 receivers.
__global__ __launch_bounds__(256) void k_layer0(
    const float* __restrict__ pos, const float* __restrict__ hA,
    unsigned short* __restrict__ apout, const unsigned short* __restrict__ Wpack) {
  __shared__ __align__(16) unsigned short sh_S[NN][136];     // 17408 B
  __shared__ __align__(16) unsigned short sh_M0T[4][32][72]; // 18432 B
  __shared__ __align__(16) unsigned short sh_rbh[4][NN][8];  // 4096 B
  __shared__ __align__(16) unsigned short sh_ub[4][4][NN];   // 2048 B

  int blk = blockIdx.x;
  int b = blk >> 4, rp4 = blk & 15;
  int r0 = rp4 * 4;
  int tid = threadIdx.x;
  int w = tid >> 6, lane = tid & 63;
  int nlo = lane & 15, quad = lane >> 4;
  const short8 zero8 = {0, 0, 0, 0, 0, 0, 0, 0};

  f32x4 hbv[4][2];
#pragma unroll
  for (int mt = 0; mt < 4; ++mt)
#pragma unroll
    for (int nt = 0; nt < 2; ++nt)
#pragma unroll
      for (int reg = 0; reg < 4; ++reg)
        hbv[mt][nt][reg] =
            hA[((size_t)b * NN + mt * 16 + quad * 4 + reg) * HH + w * 32 + nt * 16 + nlo];

  const unsigned short* Wr1p = Wpack + WR1OFF;
  short8 bw[2];
#pragma unroll
  for (int nt = 0; nt < 2; ++nt)
    bw[nt] = *(const short8*)&Wr1p[((w * 32 + nt * 16 + nlo) * 4 + quad) * 8];
  const unsigned short* Bbase = Wpack;
  short8 bfr[4][2];
#pragma unroll
  for (int kt = 0; kt < 4; ++kt)
#pragma unroll
    for (int nt = 0; nt < 2; ++nt)
      bfr[kt][nt] = *(const short8*)&Bbase[((kt * 128 + w * 32 + nt * 16 + nlo) * 4 + quad) * 8];

  // ---- Stage A: all 4 receivers at once ----
  {
    int s = tid & 63;
    int ri4 = tid >> 6;
    int r = r0 + ri4;
    const float* pb = pos + b * NN * 3;
    float dx = pb[r * 3 + 0] - pb[s * 3 + 0];
    float dy = pb[r * 3 + 1] - pb[s * 3 + 1];
    float dz = pb[r * 3 + 2] - pb[s * 3 + 2];
    float rr = sqrtf(dx * dx + dy * dy + dz * dz + 1e-12f);
    float inv = __builtin_amdgcn_rcpf(rr);
    const float invAvg = 1.0f / 63.0f;
    float ia = inv * invAvg;
    sh_ub[ri4][0][s] = bf1(invAvg);
    sh_ub[ri4][1][s] = bf1(dx * ia);
    sh_ub[ri4][2][s] = bf1(dy * ia);
    sh_ub[ri4][3][s] = bf1(dz * ia);
    const float PI_OVER_5 = 0.628318530717958647692f;
    float fc = (s != r && rr < 5.0f) ? 0.5f * (__cosf(PI_OVER_5 * rr) + 1.0f) : 0.0f;
    float base = PI_OVER_5 * rr;
    float sc = inv * fc;
#pragma unroll
    for (int k0 = 0; k0 < 8; k0 += 4) {
      float v0 = __sinf((float)(k0 + 1) * base) * sc;
      float v1 = __sinf((float)(k0 + 2) * base) * sc;
      float v2 = __sinf((float)(k0 + 3) * base) * sc;
      float v3 = __sinf((float)(k0 + 4) * base) * sc;
      *(unsigned*)&sh_rbh[ri4][s][k0]     = bf2(v0, v1);
      *(unsigned*)&sh_rbh[ri4][s][k0 + 2] = bf2(v2, v3);
    }
  }
  __syncthreads();

#pragma unroll
  for (int rsel = 0; rsel < 4; ++rsel) {
    // ---- Stage B ----
#pragma unroll
    for (int mtp = 0; mtp < 2; ++mtp) {
      f32x4 Cs[2][2];
#pragma unroll
      for (int mi = 0; mi < 2; ++mi)
#pragma unroll
        for (int nt = 0; nt < 2; ++nt) Cs[mi][nt] = (f32x4){0.f, 0.f, 0.f, 0.f};
#pragma unroll
      for (int mi = 0; mi < 2; ++mi) {
        int mt = mtp * 2 + mi;
        short8 afr = (quad == 0) ? *(const short8*)&sh_rbh[rsel][mt * 16 + nlo][0] : zero8;
#pragma unroll
        for (int nt = 0; nt < 2; ++nt)
          Cs[mi][nt] = __builtin_amdgcn_mfma_f32_16x16x32_bf16(afr, bw[nt], Cs[mi][nt], 0, 0, 0);
      }
#pragma unroll
      for (int mi = 0; mi < 2; ++mi)
#pragma unroll
        for (int nt = 0; nt < 2; ++nt)
#pragma unroll
          for (int reg = 0; reg < 4; ++reg) {
            int s = (mtp * 2 + mi) * 16 + quad * 4 + reg;
            int c = w * 32 + nt * 16 + nlo;
            sh_S[s][c] = bf1(silu_f(Cs[mi][nt][reg]));
          }
    }
    __syncthreads();

    // ---- Main GEMM + M0T ----
#pragma unroll
    for (int mt = 0; mt < 4; ++mt) {
      short8 afr[4];
      int s_a = mt * 16 + nlo;
#pragma unroll
      for (int kt = 0; kt < 4; ++kt)
        afr[kt] = *(const short8*)&sh_S[s_a][kt * 32 + quad * 8];
#pragma unroll
      for (int nt = 0; nt < 2; ++nt) {
        f32x4 C = {0.f, 0.f, 0.f, 0.f};
#pragma unroll
        for (int kt = 0; kt < 4; ++kt)
          C = __builtin_amdgcn_mfma_f32_16x16x32_bf16(afr[kt], bfr[kt][nt], C, 0, 0, 0);
        f32x4 m0 = C * hbv[mt][nt];
        u32x2 pk;
        pk.x = bf2(m0[0], m0[1]);
        pk.y = bf2(m0[2], m0[3]);
        *(u32x2*)&sh_M0T[w][nt * 16 + nlo][mt * 16 + quad * 4] = pk;
      }
    }
    // ---- U-GEMM -> global planes 0-3 ----
    {
      short8 au[2];
#pragma unroll
      for (int kt = 0; kt < 2; ++kt)
        au[kt] = (nlo < 4) ? *(const short8*)&sh_ub[rsel][nlo][kt * 32 + quad * 8] : zero8;
      f32x4 Cu[2] = {{0, 0, 0, 0}, {0, 0, 0, 0}};
#pragma unroll
      for (int nt = 0; nt < 2; ++nt)
#pragma unroll
        for (int kt = 0; kt < 2; ++kt) {
          short8 bm = *(const short8*)&sh_M0T[w][nt * 16 + nlo][kt * 32 + quad * 8];
          Cu[nt] = __builtin_amdgcn_mfma_f32_16x16x32_bf16(au[kt], bm, Cu[nt], 0, 0, 0);
        }
      if (quad == 0) {
#pragma unroll
        for (int nt = 0; nt < 2; ++nt) {
          size_t base = (size_t)(b * NN + r0 + rsel) * HH + w * 32 + nt * 16 + nlo;
#pragma unroll
          for (int reg = 0; reg < 4; ++reg)
            apout[reg * PLANE + base] = bf1(Cu[nt][reg]);
        }
      }
    }
    if (rsel != 3) __syncthreads();
  }
}

// Fused layer-1 + update/readout (R10 version, kept: Ch = hbv rows, planes 4-7
// in LDS). Grid 512: block blk = (b = blk>>3, u8 = blk&7), rows [blk*8, blk*8+8).
__global__ __launch_bounds__(256) void k_fused(
    const float* __restrict__ pos, const float* __restrict__ hA,
    unsigned short* __restrict__ apbf, const unsigned short* __restrict__ Wpack,
    const float* __restrict__ fs, float* __restrict__ out) {
  __shared__ __align__(16) unsigned char smem[50688];
  unsigned short (*sh_S)[136]      = (unsigned short (*)[136])smem;               // 17408 B
  unsigned short (*sh_M0T)[32][72] = (unsigned short (*)[32][72])(smem + 17408);  // 18432 B
  unsigned short (*sh_rbh)[NN][8]  = (unsigned short (*)[NN][8])(smem + 35840);   // 4096 B
  unsigned short (*sh_ub)[4][NN]   = (unsigned short (*)[4][NN])(smem + 39936);   // 2048 B
  unsigned short (*sh_a47)[8][136] = (unsigned short (*)[8][136])(smem + 41984);  // 8704 B

  int blk = blockIdx.x;
  int b = blk >> 3, u8 = blk & 7;
  int tid = threadIdx.x;
  int w = tid >> 6, lane = tid & 63;
  int nlo = lane & 15, quad = lane >> 4;
  const short8 zero8 = {0, 0, 0, 0, 0, 0, 0, 0};

  // ---- hbv: graph h in C-reg layout ----
  f32x4 hbv[4][2];
#pragma unroll
  for (int mt = 0; mt < 4; ++mt)
#pragma unroll
    for (int nt = 0; nt < 2; ++nt)
#pragma unroll
      for (int reg = 0; reg < 4; ++reg)
        hbv[mt][nt][reg] =
            hA[((size_t)b * NN + mt * 16 + quad * 4 + reg) * HH + w * 32 + nt * 16 + nlo];

  // ---- stage a0_l0 (prior launch) and apply hbv += a0_l0 @ Wupd0 ----
  for (int i = tid; i < NN * 64; i += 256) {
    int s = i >> 6, c2 = (i & 63) * 2;
    *(unsigned*)&sh_S[s][c2] =
        *(const unsigned*)&apbf[((size_t)b * NN + s) * HH + c2];
  }
  __syncthreads();
  {
    const unsigned short* Bu = Wpack + 2 * 16384;
#pragma unroll
    for (int mt = 0; mt < 4; ++mt) {
      short8 afr[4];
#pragma unroll
      for (int kt = 0; kt < 4; ++kt)
        afr[kt] = *(const short8*)&sh_S[mt * 16 + nlo][kt * 32 + quad * 8];
#pragma unroll
      for (int nt = 0; nt < 2; ++nt)
#pragma unroll
        for (int kt = 0; kt < 4; ++kt) {
          short8 bfr2 = *(const short8*)&Bu[((kt * 128 + w * 32 + nt * 16 + nlo) * 4 + quad) * 8];
          hbv[mt][nt] = __builtin_amdgcn_mfma_f32_16x16x32_bf16(afr[kt], bfr2, hbv[mt][nt], 0, 0, 0);
        }
    }
  }
  __syncthreads();   // sh_S reads done before Stage B overwrites

  // ---- layer-1 fragment hoists ----
  const unsigned short* Wr1p = Wpack + WR1OFF + 4096;
  short8 bw[2];
#pragma unroll
  for (int nt = 0; nt < 2; ++nt)
    bw[nt] = *(const short8*)&Wr1p[((w * 32 + nt * 16 + nlo) * 4 + quad) * 8];
  const unsigned short* Bbase = Wpack + 16384;
  short8 bfr[4][2];
#pragma unroll
  for (int kt = 0; kt < 4; ++kt)
#pragma unroll
    for (int nt = 0; nt < 2; ++nt)
      bfr[kt][nt] = *(const short8*)&Bbase[((kt * 128 + w * 32 + nt * 16 + nlo) * 4 + quad) * 8];

  for (int unit = 0; unit < 2; ++unit) {
    int r0 = u8 * 8 + unit * 4;

    // ---- Stage A: 4 receivers of this unit ----
    {
      int s = tid & 63;
      int ri4 = tid >> 6;
      int r = r0 + ri4;
      const float* pb = pos + b * NN * 3;
      float dx = pb[r * 3 + 0] - pb[s * 3 + 0];
      float dy = pb[r * 3 + 1] - pb[s * 3 + 1];
      float dz = pb[r * 3 + 2] - pb[s * 3 + 2];
      float rr = sqrtf(dx * dx + dy * dy + dz * dz + 1e-12f);
      float inv = __builtin_amdgcn_rcpf(rr);
      const float invAvg = 1.0f / 63.0f;
      float ia = inv * invAvg;
      sh_ub[ri4][0][s] = bf1(invAvg);
      sh_ub[ri4][1][s] = bf1(dx * ia);
      sh_ub[ri4][2][s] = bf1(dy * ia);
      sh_ub[ri4][3][s] = bf1(dz * ia);
      const float PI_OVER_5 = 0.628318530717958647692f;
      float fc = (s != r && rr < 5.0f) ? 0.5f * (__cosf(PI_OVER_5 * rr) + 1.0f) : 0.0f;
      float base = PI_OVER_5 * rr;
      float sc = inv * fc;
#pragma unroll
      for (int k0 = 0; k0 < 8; k0 += 4) {
        float v0 = __sinf((float)(k0 + 1) * base) * sc;
        float v1 = __sinf((float)(k0 + 2) * base) * sc;
        float v2 = __sinf((float)(k0 + 3) * base) * sc;
        float v3 = __sinf((float)(k0 + 4) * base) * sc;
        *(unsigned*)&sh_rbh[ri4][s][k0]     = bf2(v0, v1);
        *(unsigned*)&sh_rbh[ri4][s][k0 + 2] = bf2(v2, v3);
      }
    }
    __syncthreads();

#pragma unroll
    for (int rsel = 0; rsel < 4; ++rsel) {
      int lr = unit * 4 + rsel;   // local row 0..7
      // ---- Stage B ----
#pragma unroll
      for (int mtp = 0; mtp < 2; ++mtp) {
        f32x4 Cs[2][2];
#pragma unroll
        for (int mi = 0; mi < 2; ++mi)
#pragma unroll
          for (int nt = 0; nt < 2; ++nt) Cs[mi][nt] = (f32x4){0.f, 0.f, 0.f, 0.f};
#pragma unroll
        for (int mi = 0; mi < 2; ++mi) {
          int mt = mtp * 2 + mi;
          short8 afr = (quad == 0) ? *(const short8*)&sh_rbh[rsel][mt * 16 + nlo][0] : zero8;
#pragma unroll
          for (int nt = 0; nt < 2; ++nt)
            Cs[mi][nt] = __builtin_amdgcn_mfma_f32_16x16x32_bf16(afr, bw[nt], Cs[mi][nt], 0, 0, 0);
        }
#pragma unroll
        for (int mi = 0; mi < 2; ++mi)
#pragma unroll
          for (int nt = 0; nt < 2; ++nt)
#pragma unroll
            for (int reg = 0; reg < 4; ++reg) {
              int s = (mtp * 2 + mi) * 16 + quad * 4 + reg;
              int c = w * 32 + nt * 16 + nlo;
              sh_S[s][c] = bf1(silu_f(Cs[mi][nt][reg]));
            }
      }
      __syncthreads();

      // ---- Main GEMM + M0T ----
#pragma unroll
      for (int mt = 0; mt < 4; ++mt) {
        short8 afr[4];
        int s_a = mt * 16 + nlo;
#pragma unroll
        for (int kt = 0; kt < 4; ++kt)
          afr[kt] = *(const short8*)&sh_S[s_a][kt * 32 + quad * 8];
#pragma unroll
        for (int nt = 0; nt < 2; ++nt) {
          f32x4 C = {0.f, 0.f, 0.f, 0.f};
#pragma unroll
          for (int kt = 0; kt < 4; ++kt)
            C = __builtin_amdgcn_mfma_f32_16x16x32_bf16(afr[kt], bfr[kt][nt], C, 0, 0, 0);
          f32x4 m0 = C * hbv[mt][nt];
          u32x2 pk;
          pk.x = bf2(m0[0], m0[1]);
          pk.y = bf2(m0[2], m0[3]);
          *(u32x2*)&sh_M0T[w][nt * 16 + nlo][mt * 16 + quad * 4] = pk;
        }
      }
      // ---- U-GEMM -> sh_a47 (LDS only, no global) ----
      {
        short8 au[2];
#pragma unroll
        for (int kt = 0; kt < 2; ++kt)
          au[kt] = (nlo < 4) ? *(const short8*)&sh_ub[rsel][nlo][kt * 32 + quad * 8] : zero8;
        f32x4 Cu[2] = {{0, 0, 0, 0}, {0, 0, 0, 0}};
#pragma unroll
        for (int nt = 0; nt < 2; ++nt)
#pragma unroll
          for (int kt = 0; kt < 2; ++kt) {
            short8 bm = *(const short8*)&sh_M0T[w][nt * 16 + nlo][kt * 32 + quad * 8];
            Cu[nt] = __builtin_amdgcn_mfma_f32_16x16x32_bf16(au[kt], bm, Cu[nt], 0, 0, 0);
          }
        if (quad == 0) {
#pragma unroll
          for (int nt = 0; nt < 2; ++nt) {
            int c = w * 32 + nt * 16 + nlo;
#pragma unroll
            for (int reg = 0; reg < 4; ++reg)
              sh_a47[reg][lr][c] = bf1(Cu[nt][reg]);
          }
        }
      }
      __syncthreads();   // sh_S/rbh/ub safe to overwrite; a47 visible later
    }
  }

  // ---- update + readout for rows [blk*8, blk*8+8) ----
  {
    unsigned short (*sh_a03)[8][136] = (unsigned short (*)[8][136])smem;          // planes 1-3
    unsigned short (*sh_h)[136]      = (unsigned short (*)[136])(smem + 8704);    // 2176 B
    float (*red)[8][3]               = (float (*)[8][3])(smem + 8704 + 2176);     // 384 B
    int row0 = blk * 8;
    for (int i = tid; i < 3 * 8 * 64; i += 256) {
      int p = i >> 9, rr = (i >> 6) & 7, c2 = (i & 63) * 2;
      *(unsigned*)&sh_a03[p + 1][rr][c2] =
          *(const unsigned*)&apbf[(p + 1) * PLANE + (size_t)(row0 + rr) * HH + c2];
    }
    // Ch from hbv: rows u8*8+quad*4+reg live in hbv[u8>>1], quads 0-1 (even u8)
    // or quads 2-3 (odd u8; fetch via lane^32 shuffle). Unrolled select avoids
    // runtime-indexed vector array (scratch hazard).
    f32x4 hsel[2];
#pragma unroll
    for (int mt = 0; mt < 4; ++mt)
      if (mt == (u8 >> 1)) { hsel[0] = hbv[mt][0]; hsel[1] = hbv[mt][1]; }
    f32x4 Ch[2];
#pragma unroll
    for (int nt = 0; nt < 2; ++nt)
#pragma unroll
      for (int reg = 0; reg < 4; ++reg) {
        float own = hsel[nt][reg];
        float swp = __shfl(own, lane ^ 32);
        Ch[nt][reg] = (quad < 2) ? ((u8 & 1) ? swp : own) : 0.f;
      }
    __syncthreads();
    gemm8(sh_a47[0], Wpack + 3 * 16384, w, nlo, quad, Ch);   // + a0l1@Wupd1
    f32x4 Cx[2] = {{0,0,0,0},{0,0,0,0}};
    f32x4 Cy[2] = {{0,0,0,0},{0,0,0,0}};
    f32x4 Cz[2] = {{0,0,0,0},{0,0,0,0}};
    gemm8(sh_a03[1], Wpack + 4 * 16384, w, nlo, quad, Cx);
    gemm8(sh_a47[1], Wpack + 5 * 16384, w, nlo, quad, Cx);
    gemm8(sh_a03[2], Wpack + 4 * 16384, w, nlo, quad, Cy);
    gemm8(sh_a47[2], Wpack + 5 * 16384, w, nlo, quad, Cy);
    gemm8(sh_a03[3], Wpack + 4 * 16384, w, nlo, quad, Cz);
    gemm8(sh_a47[3], Wpack + 5 * 16384, w, nlo, quad, Cz);
    if (quad < 2) {
#pragma unroll
      for (int nt = 0; nt < 2; ++nt)
#pragma unroll
        for (int reg = 0; reg < 4; ++reg)
          sh_h[quad * 4 + reg][w * 32 + nt * 16 + nlo] = bf1(Ch[nt][reg]);
    }
    __syncthreads();   // sh_h ready; sh_a03[0] region free (never staged)
    unsigned short (*sh_q)[136] = sh_a03[0];
    f32x4 Cq[2] = {{0,0,0,0},{0,0,0,0}};
    gemm8(sh_h, Wpack + 6 * 16384, w, nlo, quad, Cq);
    if (quad < 2) {
#pragma unroll
      for (int nt = 0; nt < 2; ++nt)
#pragma unroll
        for (int reg = 0; reg < 4; ++reg)
          sh_q[quad * 4 + reg][w * 32 + nt * 16 + nlo] = bf1(silu_f(Cq[nt][reg]));
    }
    __syncthreads();
    f32x4 Cg[2] = {{0,0,0,0},{0,0,0,0}};
    gemm8(sh_q, Wpack + 7 * 16384, w, nlo, quad, Cg);
    float pr[3][4];
#pragma unroll
    for (int d = 0; d < 3; ++d)
#pragma unroll
      for (int reg = 0; reg < 4; ++reg) pr[d][reg] = 0.f;
#pragma unroll
    for (int nt = 0; nt < 2; ++nt)
#pragma unroll
      for (int reg = 0; reg < 4; ++reg) {
        float gv = Cg[nt][reg];
        pr[0][reg] += gv * Cx[nt][reg];
        pr[1][reg] += gv * Cy[nt][reg];
        pr[2][reg] += gv * Cz[nt][reg];
      }
#pragma unroll
    for (int off = 1; off < 16; off <<= 1)
#pragma unroll
      for (int d = 0; d < 3; ++d)
#pragma unroll
        for (int reg = 0; reg < 4; ++reg)
          pr[d][reg] += __shfl_xor(pr[d][reg], off);
    if (nlo == 0 && quad < 2) {
#pragma unroll
      for (int d = 0; d < 3; ++d)
#pragma unroll
        for (int reg = 0; reg < 4; ++reg)
          red[w][quad * 4 + reg][d] = pr[d][reg];
    }
    __syncthreads();
    if (tid < 24) {
      int row = tid / 3, d = tid % 3;
      float s = red[0][row][d] + red[1][row][d] + red[2][row][d] + red[3][row][d];
      out[(size_t)(row0 + row) * 3 + d] = s * fs[0];
    }
  }
}

extern "C" void kernel_launch(void* const* d_in, const int* in_sizes, int n_in,
                              void* d_out, int out_size, void* d_ws, size_t ws_size,
                              hipStream_t stream) {
  const float* pos  = (const float*)d_in[0];
  const int*   z    = (const int*)d_in[1];
  const float* gf   = (const float*)d_in[2];
  const float* emb  = (const float*)d_in[3];
  const float* Wt   = (const float*)d_in[4];
  const float* Wr1  = (const float*)d_in[5];
  const float* Wr2  = (const float*)d_in[6];
  const float* Wupd = (const float*)d_in[7];
  const float* Wmix = (const float*)d_in[8];
  const float* Wg1  = (const float*)d_in[9];
  const float* Wg2  = (const float*)d_in[10];
  const float* fs   = (const float*)d_in[11];
  float* out = (float*)d_out;

  float* ws = (float*)d_ws;
  float* hA = ws;                                         // 2 MB
  unsigned short* apbf = (unsigned short*)(ws + PLANE);   // bf16 planes (0-3 used)
  unsigned short* Wpack = (unsigned short*)(ws + 5 * PLANE);  // 272 KB

  k_init<<<dim3(256), dim3(256), 0, stream>>>(emb, z, gf, Wt, Wr1, Wr2, Wupd,
                                              Wmix, Wg1, Wg2, hA, Wpack);
  k_layer0<<<dim3(BB * 16), dim3(256), 0, stream>>>(pos, hA, apbf, Wpack);
  k_fused<<<dim3(512), dim3(256), 0, stream>>>(pos, hA, apbf, Wpack, fs, out);
}

// Round 12
// 139.452 us; speedup vs baseline: 1.0271x; 1.0096x over previous
//
#include <hip/hip_runtime.h>
#include <math.h>

#define NN 64      // nodes per graph
#define HH 128     // hidden channels
#define NBB 8      // bessel basis
#define TT 32      // time embedding dim
#define BB 64      // batch
#define NROW (BB * NN)        // 4096 total rows
#define PLANE ((size_t)NROW * HH)   // 524288
#define WR1OFF (8 * 16384)    // Wr1 B-frag slabs in Wpack (2 x 4096)

typedef __attribute__((ext_vector_type(8))) short short8;
typedef __attribute__((ext_vector_type(4))) float f32x4;
typedef __attribute__((ext_vector_type(2))) unsigned int u32x2;

__device__ __forceinline__ float silu_f(float x) {
  return x * __builtin_amdgcn_rcpf(1.0f + __expf(-x));
}

__device__ __forceinline__ unsigned short bf1(float x) {
  __bf16 h = (__bf16)x;
  return *(unsigned short*)&h;
}
__device__ __forceinline__ unsigned bf2(float lo, float hi) {
  return (unsigned)bf1(lo) | ((unsigned)bf1(hi) << 16);
}

// 8-row MFMA GEMM tile: A rows 8..15 zero. C map: row=quad*4+reg (<8), col=w*32+nt*16+nlo.
__device__ __forceinline__ void gemm8(
    const unsigned short (*sA)[136], const unsigned short* __restrict__ Bp,
    int w, int nlo, int quad, f32x4 C[2]) {
  const short8 z8 = {0, 0, 0, 0, 0, 0, 0, 0};
  short8 afr[4];
#pragma unroll
  for (int kt = 0; kt < 4; ++kt)
    afr[kt] = (nlo < 8) ? *(const short8*)&sA[nlo][kt * 32 + quad * 8] : z8;
#pragma unroll
  for (int nt = 0; nt < 2; ++nt)
#pragma unroll
    for (int kt = 0; kt < 4; ++kt) {
      short8 bfr = *(const short8*)&Bp[((kt * 128 + w * 32 + nt * 16 + nlo) * 4 + quad) * 8];
      C[nt] = __builtin_amdgcn_mfma_f32_16x16x32_bf16(afr[kt], bfr, C[nt], 0, 0, 0);
    }
}

// Same but with pre-hoisted B-fragments (update-phase Wmix reuse across x/y/z).
__device__ __forceinline__ void gemm8_pre(
    const unsigned short (*sA)[136], const short8 Bf[4][2],
    int nlo, int quad, f32x4 C[2]) {
  const short8 z8 = {0, 0, 0, 0, 0, 0, 0, 0};
  short8 afr[4];
#pragma unroll
  for (int kt = 0; kt < 4; ++kt)
    afr[kt] = (nlo < 8) ? *(const short8*)&sA[nlo][kt * 32 + quad * 8] : z8;
#pragma unroll
  for (int nt = 0; nt < 2; ++nt)
#pragma unroll
    for (int kt = 0; kt < 4; ++kt)
      C[nt] = __builtin_amdgcn_mfma_f32_16x16x32_bf16(afr[kt], Bf[kt][nt], C[nt], 0, 0, 0);
}

// Grid 256. Pack all weights -> bf16 MFMA-B-frag order; blocks<64 init h. (R2-exact)
__global__ __launch_bounds__(256) void k_init(
    const float* __restrict__ emb, const int* __restrict__ z,
    const float* __restrict__ gf, const float* __restrict__ Wt,
    const float* __restrict__ Wr1, const float* __restrict__ Wr2,
    const float* __restrict__ Wupd, const float* __restrict__ Wmix,
    const float* __restrict__ Wg1, const float* __restrict__ Wg2,
    float* __restrict__ h, unsigned short* __restrict__ Wpack) {
  __shared__ float tvec[HH];
  __shared__ int sz[NN];
  int b4 = blockIdx.x, tid = threadIdx.x;
  {
    int p2 = b4 * 256 + tid;
    int p = p2 * 2;
    int m = p >> 14;
    int j = p & 7;
    int q = (p >> 3) & 3;
    int n = (p >> 5) & 127;
    int kt = (p >> 12) & 3;
    int k = kt * 32 + q * 8 + j;
    const float* src;
    int base;
    if (m < 2) { src = Wr2; base = m * 16384; }
    else if (m < 4) { src = Wupd; base = (m - 2) * 16384; }
    else if (m < 6) { src = Wmix; base = (m - 4) * 16384; }
    else if (m == 6) { src = Wg1; base = 0; }
    else { src = Wg2; base = 0; }
    float v0 = src[base + k * 128 + n];
    float v1 = src[base + (k + 1) * 128 + n];
    *(unsigned*)&Wpack[p] = bf2(v0, v1);
  }
  if (tid < 32) {
    int e = b4 * 32 + tid;
    int l = e >> 12, p = e & 4095;
    int n = p >> 5, q = (p >> 3) & 3, j = p & 7;
    float val = (q == 0) ? Wr1[l * NBB * HH + j * HH + n] : 0.f;
    Wpack[WR1OFF + l * 4096 + p] = bf1(val);
  }
  if (b4 < 64) {
    int b = b4;
    if (tid < NN) sz[tid] = z[b * NN + tid];
    if (tid < HH) {
      float acc = 0.f;
#pragma unroll
      for (int k = 0; k < TT; ++k) acc += gf[b * TT + k] * Wt[k * HH + tid];
      tvec[tid] = acc;
    }
    __syncthreads();
    for (int i = tid; i < NN * HH; i += 256) {
      int n = i >> 7, c = i & 127;
      h[(size_t)b * NN * HH + i] = emb[sz[n] * HH + c] + tvec[c];
    }
  }
}

// Layer 0 (R9-exact). Grid BB*16 = 1024, 4 receivers/block: 41984 B LDS -> 3
// blocks/CU = 12 waves/CU resident. Single Stage-A phase covers all 4 receivers.
__global__ __launch_bounds__(256) void k_layer0(
    const float* __restrict__ pos, const float* __restrict__ hA,
    unsigned short* __restrict__ apout, const unsigned short* __restrict__ Wpack) {
  __shared__ __align__(16) unsigned short sh_S[NN][136];     // 17408 B
  __shared__ __align__(16) unsigned short sh_M0T[4][32][72]; // 18432 B
  __shared__ __align__(16) unsigned short sh_rbh[4][NN][8];  // 4096 B
  __shared__ __align__(16) unsigned short sh_ub[4][4][NN];   // 2048 B

  int blk = blockIdx.x;
  int b = blk >> 4, rp4 = blk & 15;
  int r0 = rp4 * 4;
  int tid = threadIdx.x;
  int w = tid >> 6, lane = tid & 63;
  int nlo = lane & 15, quad = lane >> 4;
  const short8 zero8 = {0, 0, 0, 0, 0, 0, 0, 0};

  f32x4 hbv[4][2];
#pragma unroll
  for (int mt = 0; mt < 4; ++mt)
#pragma unroll
    for (int nt = 0; nt < 2; ++nt)
#pragma unroll
      for (int reg = 0; reg < 4; ++reg)
        hbv[mt][nt][reg] =
            hA[((size_t)b * NN + mt * 16 + quad * 4 + reg) * HH + w * 32 + nt * 16 + nlo];

  const unsigned short* Wr1p = Wpack + WR1OFF;
  short8 bw[2];
#pragma unroll
  for (int nt = 0; nt < 2; ++nt)
    bw[nt] = *(const short8*)&Wr1p[((w * 32 + nt * 16 + nlo) * 4 + quad) * 8];
  const unsigned short* Bbase = Wpack;
  short8 bfr[4][2];
#pragma unroll
  for (int kt = 0; kt < 4; ++kt)
#pragma unroll
    for (int nt = 0; nt < 2; ++nt)
      bfr[kt][nt] = *(const short8*)&Bbase[((kt * 128 + w * 32 + nt * 16 + nlo) * 4 + quad) * 8];

  // ---- Stage A: all 4 receivers at once ----
  {
    int s = tid & 63;
    int ri4 = tid >> 6;
    int r = r0 + ri4;
    const float* pb = pos + b * NN * 3;
    float dx = pb[r * 3 + 0] - pb[s * 3 + 0];
    float dy = pb[r * 3 + 1] - pb[s * 3 + 1];
    float dz = pb[r * 3 + 2] - pb[s * 3 + 2];
    float rr = sqrtf(dx * dx + dy * dy + dz * dz + 1e-12f);
    float inv = __builtin_amdgcn_rcpf(rr);
    const float invAvg = 1.0f / 63.0f;
    float ia = inv * invAvg;
    sh_ub[ri4][0][s] = bf1(invAvg);
    sh_ub[ri4][1][s] = bf1(dx * ia);
    sh_ub[ri4][2][s] = bf1(dy * ia);
    sh_ub[ri4][3][s] = bf1(dz * ia);
    const float PI_OVER_5 = 0.628318530717958647692f;
    float fc = (s != r && rr < 5.0f) ? 0.5f * (__cosf(PI_OVER_5 * rr) + 1.0f) : 0.0f;
    float base = PI_OVER_5 * rr;
    float sc = inv * fc;
#pragma unroll
    for (int k0 = 0; k0 < 8; k0 += 4) {
      float v0 = __sinf((float)(k0 + 1) * base) * sc;
      float v1 = __sinf((float)(k0 + 2) * base) * sc;
      float v2 = __sinf((float)(k0 + 3) * base) * sc;
      float v3 = __sinf((float)(k0 + 4) * base) * sc;
      *(unsigned*)&sh_rbh[ri4][s][k0]     = bf2(v0, v1);
      *(unsigned*)&sh_rbh[ri4][s][k0 + 2] = bf2(v2, v3);
    }
  }
  __syncthreads();

#pragma unroll
  for (int rsel = 0; rsel < 4; ++rsel) {
    // ---- Stage B ----
#pragma unroll
    for (int mtp = 0; mtp < 2; ++mtp) {
      f32x4 Cs[2][2];
#pragma unroll
      for (int mi = 0; mi < 2; ++mi)
#pragma unroll
        for (int nt = 0; nt < 2; ++nt) Cs[mi][nt] = (f32x4){0.f, 0.f, 0.f, 0.f};
#pragma unroll
      for (int mi = 0; mi < 2; ++mi) {
        int mt = mtp * 2 + mi;
        short8 afr = (quad == 0) ? *(const short8*)&sh_rbh[rsel][mt * 16 + nlo][0] : zero8;
#pragma unroll
        for (int nt = 0; nt < 2; ++nt)
          Cs[mi][nt] = __builtin_amdgcn_mfma_f32_16x16x32_bf16(afr, bw[nt], Cs[mi][nt], 0, 0, 0);
      }
#pragma unroll
      for (int mi = 0; mi < 2; ++mi)
#pragma unroll
        for (int nt = 0; nt < 2; ++nt)
#pragma unroll
          for (int reg = 0; reg < 4; ++reg) {
            int s = (mtp * 2 + mi) * 16 + quad * 4 + reg;
            int c = w * 32 + nt * 16 + nlo;
            sh_S[s][c] = bf1(silu_f(Cs[mi][nt][reg]));
          }
    }
    __syncthreads();

    // ---- Main GEMM + M0T ----
#pragma unroll
    for (int mt = 0; mt < 4; ++mt) {
      short8 afr[4];
      int s_a = mt * 16 + nlo;
#pragma unroll
      for (int kt = 0; kt < 4; ++kt)
        afr[kt] = *(const short8*)&sh_S[s_a][kt * 32 + quad * 8];
#pragma unroll
      for (int nt = 0; nt < 2; ++nt) {
        f32x4 C = {0.f, 0.f, 0.f, 0.f};
#pragma unroll
        for (int kt = 0; kt < 4; ++kt)
          C = __builtin_amdgcn_mfma_f32_16x16x32_bf16(afr[kt], bfr[kt][nt], C, 0, 0, 0);
        f32x4 m0 = C * hbv[mt][nt];
        u32x2 pk;
        pk.x = bf2(m0[0], m0[1]);
        pk.y = bf2(m0[2], m0[3]);
        *(u32x2*)&sh_M0T[w][nt * 16 + nlo][mt * 16 + quad * 4] = pk;
      }
    }
    // ---- U-GEMM -> global planes 0-3 ----
    {
      short8 au[2];
#pragma unroll
      for (int kt = 0; kt < 2; ++kt)
        au[kt] = (nlo < 4) ? *(const short8*)&sh_ub[rsel][nlo][kt * 32 + quad * 8] : zero8;
      f32x4 Cu[2] = {{0, 0, 0, 0}, {0, 0, 0, 0}};
#pragma unroll
      for (int nt = 0; nt < 2; ++nt)
#pragma unroll
        for (int kt = 0; kt < 2; ++kt) {
          short8 bm = *(const short8*)&sh_M0T[w][nt * 16 + nlo][kt * 32 + quad * 8];
          Cu[nt] = __builtin_amdgcn_mfma_f32_16x16x32_bf16(au[kt], bm, Cu[nt], 0, 0, 0);
        }
      if (quad == 0) {
#pragma unroll
        for (int nt = 0; nt < 2; ++nt) {
          size_t base = (size_t)(b * NN + r0 + rsel) * HH + w * 32 + nt * 16 + nlo;
#pragma unroll
          for (int reg = 0; reg < 4; ++reg)
            apout[reg * PLANE + base] = bf1(Cu[nt][reg]);
        }
      }
    }
    if (rsel != 3) __syncthreads();
  }
}

// Fused layer-1 + update/readout (R9-exact structure: update stages planes 0-3,
// Ch from hA, planes 4-7 in LDS). Sole new delta vs R9: Wmix B-frag hoisting in
// the update phase (each Wmix fragment set loaded once, reused for x/y/z).
__global__ __launch_bounds__(256) void k_fused(
    const float* __restrict__ pos, const float* __restrict__ hA,
    unsigned short* __restrict__ apbf, const unsigned short* __restrict__ Wpack,
    const float* __restrict__ fs, float* __restrict__ out) {
  __shared__ __align__(16) unsigned char smem[50688];
  unsigned short (*sh_S)[136]      = (unsigned short (*)[136])smem;               // 17408 B
  unsigned short (*sh_M0T)[32][72] = (unsigned short (*)[32][72])(smem + 17408);  // 18432 B
  unsigned short (*sh_rbh)[NN][8]  = (unsigned short (*)[NN][8])(smem + 35840);   // 4096 B
  unsigned short (*sh_ub)[4][NN]   = (unsigned short (*)[4][NN])(smem + 39936);   // 2048 B
  unsigned short (*sh_a47)[8][136] = (unsigned short (*)[8][136])(smem + 41984);  // 8704 B

  int blk = blockIdx.x;
  int b = blk >> 3, u8 = blk & 7;
  int tid = threadIdx.x;
  int w = tid >> 6, lane = tid & 63;
  int nlo = lane & 15, quad = lane >> 4;
  const short8 zero8 = {0, 0, 0, 0, 0, 0, 0, 0};

  // ---- hbv: graph h in C-reg layout ----
  f32x4 hbv[4][2];
#pragma unroll
  for (int mt = 0; mt < 4; ++mt)
#pragma unroll
    for (int nt = 0; nt < 2; ++nt)
#pragma unroll
      for (int reg = 0; reg < 4; ++reg)
        hbv[mt][nt][reg] =
            hA[((size_t)b * NN + mt * 16 + quad * 4 + reg) * HH + w * 32 + nt * 16 + nlo];

  // ---- stage a0_l0 (prior launch) and apply hbv += a0_l0 @ Wupd0 ----
  for (int i = tid; i < NN * 64; i += 256) {
    int s = i >> 6, c2 = (i & 63) * 2;
    *(unsigned*)&sh_S[s][c2] =
        *(const unsigned*)&apbf[((size_t)b * NN + s) * HH + c2];
  }
  __syncthreads();
  {
    const unsigned short* Bu = Wpack + 2 * 16384;
#pragma unroll
    for (int mt = 0; mt < 4; ++mt) {
      short8 afr[4];
#pragma unroll
      for (int kt = 0; kt < 4; ++kt)
        afr[kt] = *(const short8*)&sh_S[mt * 16 + nlo][kt * 32 + quad * 8];
#pragma unroll
      for (int nt = 0; nt < 2; ++nt)
#pragma unroll
        for (int kt = 0; kt < 4; ++kt) {
          short8 bfr2 = *(const short8*)&Bu[((kt * 128 + w * 32 + nt * 16 + nlo) * 4 + quad) * 8];
          hbv[mt][nt] = __builtin_amdgcn_mfma_f32_16x16x32_bf16(afr[kt], bfr2, hbv[mt][nt], 0, 0, 0);
        }
    }
  }
  __syncthreads();   // sh_S reads done before Stage B overwrites

  // ---- layer-1 fragment hoists ----
  const unsigned short* Wr1p = Wpack + WR1OFF + 4096;
  short8 bw[2];
#pragma unroll
  for (int nt = 0; nt < 2; ++nt)
    bw[nt] = *(const short8*)&Wr1p[((w * 32 + nt * 16 + nlo) * 4 + quad) * 8];
  const unsigned short* Bbase = Wpack + 16384;
  short8 bfr[4][2];
#pragma unroll
  for (int kt = 0; kt < 4; ++kt)
#pragma unroll
    for (int nt = 0; nt < 2; ++nt)
      bfr[kt][nt] = *(const short8*)&Bbase[((kt * 128 + w * 32 + nt * 16 + nlo) * 4 + quad) * 8];

  for (int unit = 0; unit < 2; ++unit) {
    int r0 = u8 * 8 + unit * 4;

    // ---- Stage A: 4 receivers of this unit ----
    {
      int s = tid & 63;
      int ri4 = tid >> 6;
      int r = r0 + ri4;
      const float* pb = pos + b * NN * 3;
      float dx = pb[r * 3 + 0] - pb[s * 3 + 0];
      float dy = pb[r * 3 + 1] - pb[s * 3 + 1];
      float dz = pb[r * 3 + 2] - pb[s * 3 + 2];
      float rr = sqrtf(dx * dx + dy * dy + dz * dz + 1e-12f);
      float inv = __builtin_amdgcn_rcpf(rr);
      const float invAvg = 1.0f / 63.0f;
      float ia = inv * invAvg;
      sh_ub[ri4][0][s] = bf1(invAvg);
      sh_ub[ri4][1][s] = bf1(dx * ia);
      sh_ub[ri4][2][s] = bf1(dy * ia);
      sh_ub[ri4][3][s] = bf1(dz * ia);
      const float PI_OVER_5 = 0.628318530717958647692f;
      float fc = (s != r && rr < 5.0f) ? 0.5f * (__cosf(PI_OVER_5 * rr) + 1.0f) : 0.0f;
      float base = PI_OVER_5 * rr;
      float sc = inv * fc;
#pragma unroll
      for (int k0 = 0; k0 < 8; k0 += 4) {
        float v0 = __sinf((float)(k0 + 1) * base) * sc;
        float v1 = __sinf((float)(k0 + 2) * base) * sc;
        float v2 = __sinf((float)(k0 + 3) * base) * sc;
        float v3 = __sinf((float)(k0 + 4) * base) * sc;
        *(unsigned*)&sh_rbh[ri4][s][k0]     = bf2(v0, v1);
        *(unsigned*)&sh_rbh[ri4][s][k0 + 2] = bf2(v2, v3);
      }
    }
    __syncthreads();

#pragma unroll
    for (int rsel = 0; rsel < 4; ++rsel) {
      int lr = unit * 4 + rsel;   // local row 0..7
      // ---- Stage B ----
#pragma unroll
      for (int mtp = 0; mtp < 2; ++mtp) {
        f32x4 Cs[2][2];
#pragma unroll
        for (int mi = 0; mi < 2; ++mi)
#pragma unroll
          for (int nt = 0; nt < 2; ++nt) Cs[mi][nt] = (f32x4){0.f, 0.f, 0.f, 0.f};
#pragma unroll
        for (int mi = 0; mi < 2; ++mi) {
          int mt = mtp * 2 + mi;
          short8 afr = (quad == 0) ? *(const short8*)&sh_rbh[rsel][mt * 16 + nlo][0] : zero8;
#pragma unroll
          for (int nt = 0; nt < 2; ++nt)
            Cs[mi][nt] = __builtin_amdgcn_mfma_f32_16x16x32_bf16(afr, bw[nt], Cs[mi][nt], 0, 0, 0);
        }
#pragma unroll
        for (int mi = 0; mi < 2; ++mi)
#pragma unroll
          for (int nt = 0; nt < 2; ++nt)
#pragma unroll
            for (int reg = 0; reg < 4; ++reg) {
              int s = (mtp * 2 + mi) * 16 + quad * 4 + reg;
              int c = w * 32 + nt * 16 + nlo;
              sh_S[s][c] = bf1(silu_f(Cs[mi][nt][reg]));
            }
      }
      __syncthreads();

      // ---- Main GEMM + M0T ----
#pragma unroll
      for (int mt = 0; mt < 4; ++mt) {
        short8 afr[4];
        int s_a = mt * 16 + nlo;
#pragma unroll
        for (int kt = 0; kt < 4; ++kt)
          afr[kt] = *(const short8*)&sh_S[s_a][kt * 32 + quad * 8];
#pragma unroll
        for (int nt = 0; nt < 2; ++nt) {
          f32x4 C = {0.f, 0.f, 0.f, 0.f};
#pragma unroll
          for (int kt = 0; kt < 4; ++kt)
            C = __builtin_amdgcn_mfma_f32_16x16x32_bf16(afr[kt], bfr[kt][nt], C, 0, 0, 0);
          f32x4 m0 = C * hbv[mt][nt];
          u32x2 pk;
          pk.x = bf2(m0[0], m0[1]);
          pk.y = bf2(m0[2], m0[3]);
          *(u32x2*)&sh_M0T[w][nt * 16 + nlo][mt * 16 + quad * 4] = pk;
        }
      }
      // ---- U-GEMM -> sh_a47 (LDS only, no global) ----
      {
        short8 au[2];
#pragma unroll
        for (int kt = 0; kt < 2; ++kt)
          au[kt] = (nlo < 4) ? *(const short8*)&sh_ub[rsel][nlo][kt * 32 + quad * 8] : zero8;
        f32x4 Cu[2] = {{0, 0, 0, 0}, {0, 0, 0, 0}};
#pragma unroll
        for (int nt = 0; nt < 2; ++nt)
#pragma unroll
          for (int kt = 0; kt < 2; ++kt) {
            short8 bm = *(const short8*)&sh_M0T[w][nt * 16 + nlo][kt * 32 + quad * 8];
            Cu[nt] = __builtin_amdgcn_mfma_f32_16x16x32_bf16(au[kt], bm, Cu[nt], 0, 0, 0);
          }
        if (quad == 0) {
#pragma unroll
          for (int nt = 0; nt < 2; ++nt) {
            int c = w * 32 + nt * 16 + nlo;
#pragma unroll
            for (int reg = 0; reg < 4; ++reg)
              sh_a47[reg][lr][c] = bf1(Cu[nt][reg]);
          }
        }
      }
      __syncthreads();   // sh_S/rbh/ub safe to overwrite; a47 visible later
    }
  }

  // ---- update + readout for rows [blk*8, blk*8+8) ----
  {
    unsigned short (*sh_a03)[8][136] = (unsigned short (*)[8][136])smem;          // 8704 B
    unsigned short (*sh_h)[136]      = (unsigned short (*)[136])(smem + 8704);    // 2176 B
    float (*red)[8][3]               = (float (*)[8][3])(smem + 8704 + 2176);     // 384 B
    int row0 = blk * 8;
    for (int i = tid; i < 4 * 8 * 64; i += 256) {
      int p = i >> 9, rr = (i >> 6) & 7, c2 = (i & 63) * 2;
      *(unsigned*)&sh_a03[p][rr][c2] =
          *(const unsigned*)&apbf[p * PLANE + (size_t)(row0 + rr) * HH + c2];
    }
    f32x4 Ch[2];
#pragma unroll
    for (int nt = 0; nt < 2; ++nt)
#pragma unroll
      for (int reg = 0; reg < 4; ++reg)
        Ch[nt][reg] = (quad < 2)
            ? hA[(size_t)(row0 + quad * 4 + reg) * HH + w * 32 + nt * 16 + nlo] : 0.f;
    __syncthreads();
    gemm8(sh_a03[0], Wpack + 2 * 16384, w, nlo, quad, Ch);   // + a0l0@Wupd0
    gemm8(sh_a47[0], Wpack + 3 * 16384, w, nlo, quad, Ch);   // + a0l1@Wupd1
    f32x4 Cx[2] = {{0,0,0,0},{0,0,0,0}};
    f32x4 Cy[2] = {{0,0,0,0},{0,0,0,0}};
    f32x4 Cz[2] = {{0,0,0,0},{0,0,0,0}};
    // Wmix0 fragments hoisted once, reused for x/y/z (was 3x redundant loads).
    short8 Bmx[4][2];
#pragma unroll
    for (int kt = 0; kt < 4; ++kt)
#pragma unroll
      for (int nt = 0; nt < 2; ++nt)
        Bmx[kt][nt] = *(const short8*)&Wpack[4 * 16384 +
            ((kt * 128 + w * 32 + nt * 16 + nlo) * 4 + quad) * 8];
    gemm8_pre(sh_a03[1], Bmx, nlo, quad, Cx);
    gemm8_pre(sh_a03[2], Bmx, nlo, quad, Cy);
    gemm8_pre(sh_a03[3], Bmx, nlo, quad, Cz);
    // Wmix1 fragments (reuse the same register block).
#pragma unroll
    for (int kt = 0; kt < 4; ++kt)
#pragma unroll
      for (int nt = 0; nt < 2; ++nt)
        Bmx[kt][nt] = *(const short8*)&Wpack[5 * 16384 +
            ((kt * 128 + w * 32 + nt * 16 + nlo) * 4 + quad) * 8];
    gemm8_pre(sh_a47[1], Bmx, nlo, quad, Cx);
    gemm8_pre(sh_a47[2], Bmx, nlo, quad, Cy);
    gemm8_pre(sh_a47[3], Bmx, nlo, quad, Cz);
    if (quad < 2) {
#pragma unroll
      for (int nt = 0; nt < 2; ++nt)
#pragma unroll
        for (int reg = 0; reg < 4; ++reg)
          sh_h[quad * 4 + reg][w * 32 + nt * 16 + nlo] = bf1(Ch[nt][reg]);
    }
    __syncthreads();   // sh_h ready; sh_a03[0] free to alias
    unsigned short (*sh_q)[136] = sh_a03[0];
    f32x4 Cq[2] = {{0,0,0,0},{0,0,0,0}};
    gemm8(sh_h, Wpack + 6 * 16384, w, nlo, quad, Cq);
    if (quad < 2) {
#pragma unroll
      for (int nt = 0; nt < 2; ++nt)
#pragma unroll
        for (int reg = 0; reg < 4; ++reg)
          sh_q[quad * 4 + reg][w * 32 + nt * 16 + nlo] = bf1(silu_f(Cq[nt][reg]));
    }
    __syncthreads();
    f32x4 Cg[2] = {{0,0,0,0},{0,0,0,0}};
    gemm8(sh_q, Wpack + 7 * 16384, w, nlo, quad, Cg);
    float pr[3][4];
#pragma unroll
    for (int d = 0; d < 3; ++d)
#pragma unroll
      for (int reg = 0; reg < 4; ++reg) pr[d][reg] = 0.f;
#pragma unroll
    for (int nt = 0; nt < 2; ++nt)
#pragma unroll
      for (int reg = 0; reg < 4; ++reg) {
        float gv = Cg[nt][reg];
        pr[0][reg] += gv * Cx[nt][reg];
        pr[1][reg] += gv * Cy[nt][reg];
        pr[2][reg] += gv * Cz[nt][reg];
      }
#pragma unroll
    for (int off = 1; off < 16; off <<= 1)
#pragma unroll
      for (int d = 0; d < 3; ++d)
#pragma unroll
        for (int reg = 0; reg < 4; ++reg)
          pr[d][reg] += __shfl_xor(pr[d][reg], off);
    if (nlo == 0 && quad < 2) {
#pragma unroll
      for (int d = 0; d < 3; ++d)
#pragma unroll
        for (int reg = 0; reg < 4; ++reg)
          red[w][quad * 4 + reg][d] = pr[d][reg];
    }
    __syncthreads();
    if (tid < 24) {
      int row = tid / 3, d = tid % 3;
      float s = red[0][row][d] + red[1][row][d] + red[2][row][d] + red[3][row][d];
      out[(size_t)(row0 + row) * 3 + d] = s * fs[0];
    }
  }
}

extern "C" void kernel_launch(void* const* d_in, const int* in_sizes, int n_in,
                              void* d_out, int out_size, void* d_ws, size_t ws_size,
                              hipStream_t stream) {
  const float* pos  = (const float*)d_in[0];
  const int*   z    = (const int*)d_in[1];
  const float* gf   = (const float*)d_in[2];
  const float* emb  = (const float*)d_in[3];
  const float* Wt   = (const float*)d_in[4];
  const float* Wr1  = (const float*)d_in[5];
  const float* Wr2  = (const float*)d_in[6];
  const float* Wupd = (const float*)d_in[7];
  const float* Wmix = (const float*)d_in[8];
  const float* Wg1  = (const float*)d_in[9];
  const float* Wg2  = (const float*)d_in[10];
  const float* fs   = (const float*)d_in[11];
  float* out = (float*)d_out;

  float* ws = (float*)d_ws;
  float* hA = ws;                                         // 2 MB
  unsigned short* apbf = (unsigned short*)(ws + PLANE);   // bf16 planes (0-3 used)
  unsigned short* Wpack = (unsigned short*)(ws + 5 * PLANE);  // 272 KB

  k_init<<<dim3(256), dim3(256), 0, stream>>>(emb, z, gf, Wt, Wr1, Wr2, Wupd,
                                              Wmix, Wg1, Wg2, hA, Wpack);
  k_layer0<<<dim3(BB * 16), dim3(256), 0, stream>>>(pos, hA, apbf, Wpack);
  k_fused<<<dim3(512), dim3(256), 0, stream>>>(pos, hA, apbf, Wpack, fs, out);
}

// Round 13
// 139.215 us; speedup vs baseline: 1.0289x; 1.0017x over previous
//
#include <hip/hip_runtime.h>
#include <math.h>

#define NN 64      // nodes per graph
#define HH 128     // hidden channels
#define NBB 8      // bessel basis
#define TT 32      // time embedding dim
#define BB 64      // batch
#define NROW (BB * NN)        // 4096 total rows
#define PLANE ((size_t)NROW * HH)   // 524288
#define WR1OFF (8 * 16384)    // Wr1 B-frag slabs in Wpack (2 x 4096)

typedef __attribute__((ext_vector_type(8))) short short8;
typedef __attribute__((ext_vector_type(4))) float f32x4;
typedef __attribute__((ext_vector_type(2))) unsigned int u32x2;

__device__ __forceinline__ float silu_f(float x) {
  return x * __builtin_amdgcn_rcpf(1.0f + __expf(-x));
}

__device__ __forceinline__ unsigned short bf1(float x) {
  __bf16 h = (__bf16)x;
  return *(unsigned short*)&h;
}
__device__ __forceinline__ unsigned bf2(float lo, float hi) {
  return (unsigned)bf1(lo) | ((unsigned)bf1(hi) << 16);
}

// 8-row MFMA GEMM tile: A rows 8..15 zero. C map: row=quad*4+reg (<8), col=w*32+nt*16+nlo.
__device__ __forceinline__ void gemm8(
    const unsigned short (*sA)[136], const unsigned short* __restrict__ Bp,
    int w, int nlo, int quad, f32x4 C[2]) {
  const short8 z8 = {0, 0, 0, 0, 0, 0, 0, 0};
  short8 afr[4];
#pragma unroll
  for (int kt = 0; kt < 4; ++kt)
    afr[kt] = (nlo < 8) ? *(const short8*)&sA[nlo][kt * 32 + quad * 8] : z8;
#pragma unroll
  for (int nt = 0; nt < 2; ++nt)
#pragma unroll
    for (int kt = 0; kt < 4; ++kt) {
      short8 bfr = *(const short8*)&Bp[((kt * 128 + w * 32 + nt * 16 + nlo) * 4 + quad) * 8];
      C[nt] = __builtin_amdgcn_mfma_f32_16x16x32_bf16(afr[kt], bfr, C[nt], 0, 0, 0);
    }
}

// Same but with pre-hoisted B-fragments (update-phase Wmix reuse across x/y/z).
__device__ __forceinline__ void gemm8_pre(
    const unsigned short (*sA)[136], const short8 Bf[4][2],
    int nlo, int quad, f32x4 C[2]) {
  const short8 z8 = {0, 0, 0, 0, 0, 0, 0, 0};
  short8 afr[4];
#pragma unroll
  for (int kt = 0; kt < 4; ++kt)
    afr[kt] = (nlo < 8) ? *(const short8*)&sA[nlo][kt * 32 + quad * 8] : z8;
#pragma unroll
  for (int nt = 0; nt < 2; ++nt)
#pragma unroll
    for (int kt = 0; kt < 4; ++kt)
      C[nt] = __builtin_amdgcn_mfma_f32_16x16x32_bf16(afr[kt], Bf[kt][nt], C[nt], 0, 0, 0);
}

// Grid 256. Pack all weights -> bf16 MFMA-B-frag order; blocks<64 init h. (R2-exact)
__global__ __launch_bounds__(256) void k_init(
    const float* __restrict__ emb, const int* __restrict__ z,
    const float* __restrict__ gf, const float* __restrict__ Wt,
    const float* __restrict__ Wr1, const float* __restrict__ Wr2,
    const float* __restrict__ Wupd, const float* __restrict__ Wmix,
    const float* __restrict__ Wg1, const float* __restrict__ Wg2,
    float* __restrict__ h, unsigned short* __restrict__ Wpack) {
  __shared__ float tvec[HH];
  __shared__ int sz[NN];
  int b4 = blockIdx.x, tid = threadIdx.x;
  {
    int p2 = b4 * 256 + tid;
    int p = p2 * 2;
    int m = p >> 14;
    int j = p & 7;
    int q = (p >> 3) & 3;
    int n = (p >> 5) & 127;
    int kt = (p >> 12) & 3;
    int k = kt * 32 + q * 8 + j;
    const float* src;
    int base;
    if (m < 2) { src = Wr2; base = m * 16384; }
    else if (m < 4) { src = Wupd; base = (m - 2) * 16384; }
    else if (m < 6) { src = Wmix; base = (m - 4) * 16384; }
    else if (m == 6) { src = Wg1; base = 0; }
    else { src = Wg2; base = 0; }
    float v0 = src[base + k * 128 + n];
    float v1 = src[base + (k + 1) * 128 + n];
    *(unsigned*)&Wpack[p] = bf2(v0, v1);
  }
  if (tid < 32) {
    int e = b4 * 32 + tid;
    int l = e >> 12, p = e & 4095;
    int n = p >> 5, q = (p >> 3) & 3, j = p & 7;
    float val = (q == 0) ? Wr1[l * NBB * HH + j * HH + n] : 0.f;
    Wpack[WR1OFF + l * 4096 + p] = bf1(val);
  }
  if (b4 < 64) {
    int b = b4;
    if (tid < NN) sz[tid] = z[b * NN + tid];
    if (tid < HH) {
      float acc = 0.f;
#pragma unroll
      for (int k = 0; k < TT; ++k) acc += gf[b * TT + k] * Wt[k * HH + tid];
      tvec[tid] = acc;
    }
    __syncthreads();
    for (int i = tid; i < NN * HH; i += 256) {
      int n = i >> 7, c = i & 127;
      h[(size_t)b * NN * HH + i] = emb[sz[n] * HH + c] + tvec[c];
    }
  }
}

// Layer 0 (R9-exact). Grid BB*16 = 1024, 4 receivers/block: 41984 B LDS -> 3
// blocks/CU = 12 waves/CU resident. Single Stage-A phase covers all 4 receivers.
__global__ __launch_bounds__(256) void k_layer0(
    const float* __restrict__ pos, const float* __restrict__ hA,
    unsigned short* __restrict__ apout, const unsigned short* __restrict__ Wpack) {
  __shared__ __align__(16) unsigned short sh_S[NN][136];     // 17408 B
  __shared__ __align__(16) unsigned short sh_M0T[4][32][72]; // 18432 B
  __shared__ __align__(16) unsigned short sh_rbh[4][NN][8];  // 4096 B
  __shared__ __align__(16) unsigned short sh_ub[4][4][NN];   // 2048 B

  int blk = blockIdx.x;
  int b = blk >> 4, rp4 = blk & 15;
  int r0 = rp4 * 4;
  int tid = threadIdx.x;
  int w = tid >> 6, lane = tid & 63;
  int nlo = lane & 15, quad = lane >> 4;
  const short8 zero8 = {0, 0, 0, 0, 0, 0, 0, 0};

  f32x4 hbv[4][2];
#pragma unroll
  for (int mt = 0; mt < 4; ++mt)
#pragma unroll
    for (int nt = 0; nt < 2; ++nt)
#pragma unroll
      for (int reg = 0; reg < 4; ++reg)
        hbv[mt][nt][reg] =
            hA[((size_t)b * NN + mt * 16 + quad * 4 + reg) * HH + w * 32 + nt * 16 + nlo];

  const unsigned short* Wr1p = Wpack + WR1OFF;
  short8 bw[2];
#pragma unroll
  for (int nt = 0; nt < 2; ++nt)
    bw[nt] = *(const short8*)&Wr1p[((w * 32 + nt * 16 + nlo) * 4 + quad) * 8];
  const unsigned short* Bbase = Wpack;
  short8 bfr[4][2];
#pragma unroll
  for (int kt = 0; kt < 4; ++kt)
#pragma unroll
    for (int nt = 0; nt < 2; ++nt)
      bfr[kt][nt] = *(const short8*)&Bbase[((kt * 128 + w * 32 + nt * 16 + nlo) * 4 + quad) * 8];

  // ---- Stage A: all 4 receivers at once ----
  {
    int s = tid & 63;
    int ri4 = tid >> 6;
    int r = r0 + ri4;
    const float* pb = pos + b * NN * 3;
    float dx = pb[r * 3 + 0] - pb[s * 3 + 0];
    float dy = pb[r * 3 + 1] - pb[s * 3 + 1];
    float dz = pb[r * 3 + 2] - pb[s * 3 + 2];
    float rr = sqrtf(dx * dx + dy * dy + dz * dz + 1e-12f);
    float inv = __builtin_amdgcn_rcpf(rr);
    const float invAvg = 1.0f / 63.0f;
    float ia = inv * invAvg;
    sh_ub[ri4][0][s] = bf1(invAvg);
    sh_ub[ri4][1][s] = bf1(dx * ia);
    sh_ub[ri4][2][s] = bf1(dy * ia);
    sh_ub[ri4][3][s] = bf1(dz * ia);
    const float PI_OVER_5 = 0.628318530717958647692f;
    float fc = (s != r && rr < 5.0f) ? 0.5f * (__cosf(PI_OVER_5 * rr) + 1.0f) : 0.0f;
    float base = PI_OVER_5 * rr;
    float sc = inv * fc;
#pragma unroll
    for (int k0 = 0; k0 < 8; k0 += 4) {
      float v0 = __sinf((float)(k0 + 1) * base) * sc;
      float v1 = __sinf((float)(k0 + 2) * base) * sc;
      float v2 = __sinf((float)(k0 + 3) * base) * sc;
      float v3 = __sinf((float)(k0 + 4) * base) * sc;
      *(unsigned*)&sh_rbh[ri4][s][k0]     = bf2(v0, v1);
      *(unsigned*)&sh_rbh[ri4][s][k0 + 2] = bf2(v2, v3);
    }
  }
  __syncthreads();

#pragma unroll
  for (int rsel = 0; rsel < 4; ++rsel) {
    // ---- Stage B ----
#pragma unroll
    for (int mtp = 0; mtp < 2; ++mtp) {
      f32x4 Cs[2][2];
#pragma unroll
      for (int mi = 0; mi < 2; ++mi)
#pragma unroll
        for (int nt = 0; nt < 2; ++nt) Cs[mi][nt] = (f32x4){0.f, 0.f, 0.f, 0.f};
#pragma unroll
      for (int mi = 0; mi < 2; ++mi) {
        int mt = mtp * 2 + mi;
        short8 afr = (quad == 0) ? *(const short8*)&sh_rbh[rsel][mt * 16 + nlo][0] : zero8;
#pragma unroll
        for (int nt = 0; nt < 2; ++nt)
          Cs[mi][nt] = __builtin_amdgcn_mfma_f32_16x16x32_bf16(afr, bw[nt], Cs[mi][nt], 0, 0, 0);
      }
#pragma unroll
      for (int mi = 0; mi < 2; ++mi)
#pragma unroll
        for (int nt = 0; nt < 2; ++nt)
#pragma unroll
          for (int reg = 0; reg < 4; ++reg) {
            int s = (mtp * 2 + mi) * 16 + quad * 4 + reg;
            int c = w * 32 + nt * 16 + nlo;
            sh_S[s][c] = bf1(silu_f(Cs[mi][nt][reg]));
          }
    }
    __syncthreads();

    // ---- Main GEMM + M0T ----
#pragma unroll
    for (int mt = 0; mt < 4; ++mt) {
      short8 afr[4];
      int s_a = mt * 16 + nlo;
#pragma unroll
      for (int kt = 0; kt < 4; ++kt)
        afr[kt] = *(const short8*)&sh_S[s_a][kt * 32 + quad * 8];
#pragma unroll
      for (int nt = 0; nt < 2; ++nt) {
        f32x4 C = {0.f, 0.f, 0.f, 0.f};
#pragma unroll
        for (int kt = 0; kt < 4; ++kt)
          C = __builtin_amdgcn_mfma_f32_16x16x32_bf16(afr[kt], bfr[kt][nt], C, 0, 0, 0);
        f32x4 m0 = C * hbv[mt][nt];
        u32x2 pk;
        pk.x = bf2(m0[0], m0[1]);
        pk.y = bf2(m0[2], m0[3]);
        *(u32x2*)&sh_M0T[w][nt * 16 + nlo][mt * 16 + quad * 4] = pk;
      }
    }
    // ---- U-GEMM -> global planes 0-3 ----
    {
      short8 au[2];
#pragma unroll
      for (int kt = 0; kt < 2; ++kt)
        au[kt] = (nlo < 4) ? *(const short8*)&sh_ub[rsel][nlo][kt * 32 + quad * 8] : zero8;
      f32x4 Cu[2] = {{0, 0, 0, 0}, {0, 0, 0, 0}};
#pragma unroll
      for (int nt = 0; nt < 2; ++nt)
#pragma unroll
        for (int kt = 0; kt < 2; ++kt) {
          short8 bm = *(const short8*)&sh_M0T[w][nt * 16 + nlo][kt * 32 + quad * 8];
          Cu[nt] = __builtin_amdgcn_mfma_f32_16x16x32_bf16(au[kt], bm, Cu[nt], 0, 0, 0);
        }
      if (quad == 0) {
#pragma unroll
        for (int nt = 0; nt < 2; ++nt) {
          size_t base = (size_t)(b * NN + r0 + rsel) * HH + w * 32 + nt * 16 + nlo;
#pragma unroll
          for (int reg = 0; reg < 4; ++reg)
            apout[reg * PLANE + base] = bf1(Cu[nt][reg]);
        }
      }
    }
    if (rsel != 3) __syncthreads();
  }
}

// Fused layer-1 + update/readout, software-pipelined: sh_S double-buffered so
// StageB(k+1) and main(k) share one phase; StageA(0) folds into the a0-staging
// phase, StageA(1) into main(3) of unit 0 (au preloaded per unit). Layer-loop
// barriers 18 -> 11. LDS 68096 B (2 blocks/CU, grid-capped anyway).
__global__ __launch_bounds__(256) void k_fused(
    const float* __restrict__ pos, const float* __restrict__ hA,
    unsigned short* __restrict__ apbf, const unsigned short* __restrict__ Wpack,
    const float* __restrict__ fs, float* __restrict__ out) {
  __shared__ __align__(16) unsigned char smem[68096];
  unsigned short (*sh_S)[NN][136]  = (unsigned short (*)[NN][136])smem;           // 2x17408
  unsigned short (*sh_M0T)[32][72] = (unsigned short (*)[32][72])(smem + 34816);  // 18432
  unsigned short (*sh_rbh)[NN][8]  = (unsigned short (*)[NN][8])(smem + 53248);   // 4096
  unsigned short (*sh_ub)[4][NN]   = (unsigned short (*)[4][NN])(smem + 57344);   // 2048
  unsigned short (*sh_a47)[8][136] = (unsigned short (*)[8][136])(smem + 59392);  // 8704

  int blk = blockIdx.x;
  int b = blk >> 3, u8 = blk & 7;
  int tid = threadIdx.x;
  int w = tid >> 6, lane = tid & 63;
  int nlo = lane & 15, quad = lane >> 4;
  const short8 zero8 = {0, 0, 0, 0, 0, 0, 0, 0};

  // ---- hbv: graph h in C-reg layout ----
  f32x4 hbv[4][2];
#pragma unroll
  for (int mt = 0; mt < 4; ++mt)
#pragma unroll
    for (int nt = 0; nt < 2; ++nt)
#pragma unroll
      for (int reg = 0; reg < 4; ++reg)
        hbv[mt][nt][reg] =
            hA[((size_t)b * NN + mt * 16 + quad * 4 + reg) * HH + w * 32 + nt * 16 + nlo];

  auto stageA = [&](int unit) {
    int s = tid & 63;
    int ri4 = tid >> 6;
    int r = u8 * 8 + unit * 4 + ri4;
    const float* pb = pos + b * NN * 3;
    float dx = pb[r * 3 + 0] - pb[s * 3 + 0];
    float dy = pb[r * 3 + 1] - pb[s * 3 + 1];
    float dz = pb[r * 3 + 2] - pb[s * 3 + 2];
    float rr = sqrtf(dx * dx + dy * dy + dz * dz + 1e-12f);
    float inv = __builtin_amdgcn_rcpf(rr);
    const float invAvg = 1.0f / 63.0f;
    float ia = inv * invAvg;
    sh_ub[ri4][0][s] = bf1(invAvg);
    sh_ub[ri4][1][s] = bf1(dx * ia);
    sh_ub[ri4][2][s] = bf1(dy * ia);
    sh_ub[ri4][3][s] = bf1(dz * ia);
    const float PI_OVER_5 = 0.628318530717958647692f;
    float fc = (s != r && rr < 5.0f) ? 0.5f * (__cosf(PI_OVER_5 * rr) + 1.0f) : 0.0f;
    float base = PI_OVER_5 * rr;
    float sc = inv * fc;
#pragma unroll
    for (int k0 = 0; k0 < 8; k0 += 4) {
      float v0 = __sinf((float)(k0 + 1) * base) * sc;
      float v1 = __sinf((float)(k0 + 2) * base) * sc;
      float v2 = __sinf((float)(k0 + 3) * base) * sc;
      float v3 = __sinf((float)(k0 + 4) * base) * sc;
      *(unsigned*)&sh_rbh[ri4][s][k0]     = bf2(v0, v1);
      *(unsigned*)&sh_rbh[ri4][s][k0 + 2] = bf2(v2, v3);
    }
  };

  // ---- Phase 1: stage a0_l0 into sh_S[0] + StageA(unit 0) ----
  for (int i = tid; i < NN * 64; i += 256) {
    int s = i >> 6, c2 = (i & 63) * 2;
    *(unsigned*)&sh_S[0][s][c2] =
        *(const unsigned*)&apbf[((size_t)b * NN + s) * HH + c2];
  }
  stageA(0);
  __syncthreads();

  // ---- Phase 2: hbv += a0_l0 @ Wupd0 ----
  {
    const unsigned short* Bu = Wpack + 2 * 16384;
#pragma unroll
    for (int mt = 0; mt < 4; ++mt) {
      short8 afr[4];
#pragma unroll
      for (int kt = 0; kt < 4; ++kt)
        afr[kt] = *(const short8*)&sh_S[0][mt * 16 + nlo][kt * 32 + quad * 8];
#pragma unroll
      for (int nt = 0; nt < 2; ++nt)
#pragma unroll
        for (int kt = 0; kt < 4; ++kt) {
          short8 bfr2 = *(const short8*)&Bu[((kt * 128 + w * 32 + nt * 16 + nlo) * 4 + quad) * 8];
          hbv[mt][nt] = __builtin_amdgcn_mfma_f32_16x16x32_bf16(afr[kt], bfr2, hbv[mt][nt], 0, 0, 0);
        }
    }
  }

  // ---- layer-1 fragment hoists ----
  const unsigned short* Wr1p = Wpack + WR1OFF + 4096;
  short8 bw[2];
#pragma unroll
  for (int nt = 0; nt < 2; ++nt)
    bw[nt] = *(const short8*)&Wr1p[((w * 32 + nt * 16 + nlo) * 4 + quad) * 8];
  const unsigned short* Bbase = Wpack + 16384;
  short8 bfr[4][2];
#pragma unroll
  for (int kt = 0; kt < 4; ++kt)
#pragma unroll
    for (int nt = 0; nt < 2; ++nt)
      bfr[kt][nt] = *(const short8*)&Bbase[((kt * 128 + w * 32 + nt * 16 + nlo) * 4 + quad) * 8];

  auto stageB = [&](int rsel, int buf) {
#pragma unroll
    for (int mtp = 0; mtp < 2; ++mtp) {
      f32x4 Cs[2][2];
#pragma unroll
      for (int mi = 0; mi < 2; ++mi)
#pragma unroll
        for (int nt = 0; nt < 2; ++nt) Cs[mi][nt] = (f32x4){0.f, 0.f, 0.f, 0.f};
#pragma unroll
      for (int mi = 0; mi < 2; ++mi) {
        int mt = mtp * 2 + mi;
        short8 afr = (quad == 0) ? *(const short8*)&sh_rbh[rsel][mt * 16 + nlo][0] : zero8;
#pragma unroll
        for (int nt = 0; nt < 2; ++nt)
          Cs[mi][nt] = __builtin_amdgcn_mfma_f32_16x16x32_bf16(afr, bw[nt], Cs[mi][nt], 0, 0, 0);
      }
#pragma unroll
      for (int mi = 0; mi < 2; ++mi)
#pragma unroll
        for (int nt = 0; nt < 2; ++nt)
#pragma unroll
          for (int reg = 0; reg < 4; ++reg) {
            int s = (mtp * 2 + mi) * 16 + quad * 4 + reg;
            int c = w * 32 + nt * 16 + nlo;
            sh_S[buf][s][c] = bf1(silu_f(Cs[mi][nt][reg]));
          }
    }
  };

  auto mainG = [&](int buf, int lr, short8 au0, short8 au1) {
#pragma unroll
    for (int mt = 0; mt < 4; ++mt) {
      short8 afr[4];
      int s_a = mt * 16 + nlo;
#pragma unroll
      for (int kt = 0; kt < 4; ++kt)
        afr[kt] = *(const short8*)&sh_S[buf][s_a][kt * 32 + quad * 8];
#pragma unroll
      for (int nt = 0; nt < 2; ++nt) {
        f32x4 C = {0.f, 0.f, 0.f, 0.f};
#pragma unroll
        for (int kt = 0; kt < 4; ++kt)
          C = __builtin_amdgcn_mfma_f32_16x16x32_bf16(afr[kt], bfr[kt][nt], C, 0, 0, 0);
        f32x4 m0 = C * hbv[mt][nt];
        u32x2 pk;
        pk.x = bf2(m0[0], m0[1]);
        pk.y = bf2(m0[2], m0[3]);
        *(u32x2*)&sh_M0T[w][nt * 16 + nlo][mt * 16 + quad * 4] = pk;
      }
    }
    f32x4 Cu[2] = {{0, 0, 0, 0}, {0, 0, 0, 0}};
#pragma unroll
    for (int nt = 0; nt < 2; ++nt) {
      short8 bm0 = *(const short8*)&sh_M0T[w][nt * 16 + nlo][0 * 32 + quad * 8];
      Cu[nt] = __builtin_amdgcn_mfma_f32_16x16x32_bf16(au0, bm0, Cu[nt], 0, 0, 0);
      short8 bm1 = *(const short8*)&sh_M0T[w][nt * 16 + nlo][1 * 32 + quad * 8];
      Cu[nt] = __builtin_amdgcn_mfma_f32_16x16x32_bf16(au1, bm1, Cu[nt], 0, 0, 0);
    }
    if (quad == 0) {
#pragma unroll
      for (int nt = 0; nt < 2; ++nt) {
        int c = w * 32 + nt * 16 + nlo;
#pragma unroll
        for (int reg = 0; reg < 4; ++reg)
          sh_a47[reg][lr][c] = bf1(Cu[nt][reg]);
      }
    }
  };

  for (int unit = 0; unit < 2; ++unit) {
    // au preload for this unit (ub stable until next StageA, which happens in
    // the last phase of this unit -- after all reads here are in registers).
    short8 auA[4][2];
#pragma unroll
    for (int rs = 0; rs < 4; ++rs)
#pragma unroll
      for (int kt = 0; kt < 2; ++kt)
        auA[rs][kt] = (nlo < 4) ? *(const short8*)&sh_ub[rs][nlo][kt * 32 + quad * 8] : zero8;
    __syncthreads();   // unit0: sh_S[0] prologue reads done; unit1: P4(u0) done

    stageB(0, 0);
    __syncthreads();

#pragma unroll
    for (int k = 0; k < 4; ++k) {
      if (k < 3) stageB(k + 1, (k + 1) & 1);
      mainG(k & 1, unit * 4 + k, auA[k][0], auA[k][1]);
      if (k == 3 && unit == 0) stageA(1);
      __syncthreads();
    }
  }

  // ---- update + readout for rows [blk*8, blk*8+8) ----
  {
    unsigned short (*sh_a03)[8][136] = (unsigned short (*)[8][136])smem;          // 8704 B
    unsigned short (*sh_h)[136]      = (unsigned short (*)[136])(smem + 8704);    // 2176 B
    float (*red)[8][3]               = (float (*)[8][3])(smem + 8704 + 2176);     // 384 B
    int row0 = blk * 8;
    for (int i = tid; i < 4 * 8 * 64; i += 256) {
      int p = i >> 9, rr = (i >> 6) & 7, c2 = (i & 63) * 2;
      *(unsigned*)&sh_a03[p][rr][c2] =
          *(const unsigned*)&apbf[p * PLANE + (size_t)(row0 + rr) * HH + c2];
    }
    f32x4 Ch[2];
#pragma unroll
    for (int nt = 0; nt < 2; ++nt)
#pragma unroll
      for (int reg = 0; reg < 4; ++reg)
        Ch[nt][reg] = (quad < 2)
            ? hA[(size_t)(row0 + quad * 4 + reg) * HH + w * 32 + nt * 16 + nlo] : 0.f;
    __syncthreads();
    gemm8(sh_a03[0], Wpack + 2 * 16384, w, nlo, quad, Ch);   // + a0l0@Wupd0
    gemm8(sh_a47[0], Wpack + 3 * 16384, w, nlo, quad, Ch);   // + a0l1@Wupd1
    f32x4 Cx[2] = {{0,0,0,0},{0,0,0,0}};
    f32x4 Cy[2] = {{0,0,0,0},{0,0,0,0}};
    f32x4 Cz[2] = {{0,0,0,0},{0,0,0,0}};
    // Wmix0 fragments hoisted once, reused for x/y/z.
    short8 Bmx[4][2];
#pragma unroll
    for (int kt = 0; kt < 4; ++kt)
#pragma unroll
      for (int nt = 0; nt < 2; ++nt)
        Bmx[kt][nt] = *(const short8*)&Wpack[4 * 16384 +
            ((kt * 128 + w * 32 + nt * 16 + nlo) * 4 + quad) * 8];
    gemm8_pre(sh_a03[1], Bmx, nlo, quad, Cx);
    gemm8_pre(sh_a03[2], Bmx, nlo, quad, Cy);
    gemm8_pre(sh_a03[3], Bmx, nlo, quad, Cz);
#pragma unroll
    for (int kt = 0; kt < 4; ++kt)
#pragma unroll
      for (int nt = 0; nt < 2; ++nt)
        Bmx[kt][nt] = *(const short8*)&Wpack[5 * 16384 +
            ((kt * 128 + w * 32 + nt * 16 + nlo) * 4 + quad) * 8];
    gemm8_pre(sh_a47[1], Bmx, nlo, quad, Cx);
    gemm8_pre(sh_a47[2], Bmx, nlo, quad, Cy);
    gemm8_pre(sh_a47[3], Bmx, nlo, quad, Cz);
    if (quad < 2) {
#pragma unroll
      for (int nt = 0; nt < 2; ++nt)
#pragma unroll
        for (int reg = 0; reg < 4; ++reg)
          sh_h[quad * 4 + reg][w * 32 + nt * 16 + nlo] = bf1(Ch[nt][reg]);
    }
    __syncthreads();   // sh_h ready; sh_a03[0] free to alias
    unsigned short (*sh_q)[136] = sh_a03[0];
    f32x4 Cq[2] = {{0,0,0,0},{0,0,0,0}};
    gemm8(sh_h, Wpack + 6 * 16384, w, nlo, quad, Cq);
    if (quad < 2) {
#pragma unroll
      for (int nt = 0; nt < 2; ++nt)
#pragma unroll
        for (int reg = 0; reg < 4; ++reg)
          sh_q[quad * 4 + reg][w * 32 + nt * 16 + nlo] = bf1(silu_f(Cq[nt][reg]));
    }
    __syncthreads();
    f32x4 Cg[2] = {{0,0,0,0},{0,0,0,0}};
    gemm8(sh_q, Wpack + 7 * 16384, w, nlo, quad, Cg);
    float pr[3][4];
#pragma unroll
    for (int d = 0; d < 3; ++d)
#pragma unroll
      for (int reg = 0; reg < 4; ++reg) pr[d][reg] = 0.f;
#pragma unroll
    for (int nt = 0; nt < 2; ++nt)
#pragma unroll
      for (int reg = 0; reg < 4; ++reg) {
        float gv = Cg[nt][reg];
        pr[0][reg] += gv * Cx[nt][reg];
        pr[1][reg] += gv * Cy[nt][reg];
        pr[2][reg] += gv * Cz[nt][reg];
      }
#pragma unroll
    for (int off = 1; off < 16; off <<= 1)
#pragma unroll
      for (int d = 0; d < 3; ++d)
#pragma unroll
        for (int reg = 0; reg < 4; ++reg)
          pr[d][reg] += __shfl_xor(pr[d][reg], off);
    if (nlo == 0 && quad < 2) {
#pragma unroll
      for (int d = 0; d < 3; ++d)
#pragma unroll
        for (int reg = 0; reg < 4; ++reg)
          red[w][quad * 4 + reg][d] = pr[d][reg];
    }
    __syncthreads();
    if (tid < 24) {
      int row = tid / 3, d = tid % 3;
      float s = red[0][row][d] + red[1][row][d] + red[2][row][d] + red[3][row][d];
      out[(size_t)(row0 + row) * 3 + d] = s * fs[0];
    }
  }
}

extern "C" void kernel_launch(void* const* d_in, const int* in_sizes, int n_in,
                              void* d_out, int out_size, void* d_ws, size_t ws_size,
                              hipStream_t stream) {
  const float* pos  = (const float*)d_in[0];
  const int*   z    = (const int*)d_in[1];
  const float* gf   = (const float*)d_in[2];
  const float* emb  = (const float*)d_in[3];
  const float* Wt   = (const float*)d_in[4];
  const float* Wr1  = (const float*)d_in[5];
  const float* Wr2  = (const float*)d_in[6];
  const float* Wupd = (const float*)d_in[7];
  const float* Wmix = (const float*)d_in[8];
  const float* Wg1  = (const float*)d_in[9];
  const float* Wg2  = (const float*)d_in[10];
  const float* fs   = (const float*)d_in[11];
  float* out = (float*)d_out;

  float* ws = (float*)d_ws;
  float* hA = ws;                                         // 2 MB
  unsigned short* apbf = (unsigned short*)(ws + PLANE);   // bf16 planes (0-3 used)
  unsigned short* Wpack = (unsigned short*)(ws + 5 * PLANE);  // 272 KB

  k_init<<<dim3(256), dim3(256), 0, stream>>>(emb, z, gf, Wt, Wr1, Wr2, Wupd,
                                              Wmix, Wg1, Wg2, hA, Wpack);
  k_layer0<<<dim3(BB * 16), dim3(256), 0, stream>>>(pos, hA, apbf, Wpack);
  k_fused<<<dim3(512), dim3(256), 0, stream>>>(pos, hA, apbf, Wpack, fs, out);
}

// Round 14
// 138.583 us; speedup vs baseline: 1.0336x; 1.0046x over previous
//
#include <hip/hip_runtime.h>
#include <math.h>

#define NN 64      // nodes per graph
#define HH 128     // hidden channels
#define NBB 8      // bessel basis
#define TT 32      // time embedding dim
#define BB 64      // batch
#define NROW (BB * NN)        // 4096 total rows
#define PLANE ((size_t)NROW * HH)   // 524288
#define WR1OFF (8 * 16384)    // Wr1 B-frag slabs in Wpack (2 x 4096)

typedef __attribute__((ext_vector_type(8))) short short8;
typedef __attribute__((ext_vector_type(4))) float f32x4;
typedef __attribute__((ext_vector_type(2))) unsigned int u32x2;

__device__ __forceinline__ float silu_f(float x) {
  return x * __builtin_amdgcn_rcpf(1.0f + __expf(-x));
}

__device__ __forceinline__ unsigned short bf1(float x) {
  __bf16 h = (__bf16)x;
  return *(unsigned short*)&h;
}
__device__ __forceinline__ unsigned bf2(float lo, float hi) {
  return (unsigned)bf1(lo) | ((unsigned)bf1(hi) << 16);
}

// 8-row MFMA GEMM tile: A rows 8..15 zero. C map: row=quad*4+reg (<8), col=w*32+nt*16+nlo.
__device__ __forceinline__ void gemm8(
    const unsigned short (*sA)[136], const unsigned short* __restrict__ Bp,
    int w, int nlo, int quad, f32x4 C[2]) {
  const short8 z8 = {0, 0, 0, 0, 0, 0, 0, 0};
  short8 afr[4];
#pragma unroll
  for (int kt = 0; kt < 4; ++kt)
    afr[kt] = (nlo < 8) ? *(const short8*)&sA[nlo][kt * 32 + quad * 8] : z8;
#pragma unroll
  for (int nt = 0; nt < 2; ++nt)
#pragma unroll
    for (int kt = 0; kt < 4; ++kt) {
      short8 bfr = *(const short8*)&Bp[((kt * 128 + w * 32 + nt * 16 + nlo) * 4 + quad) * 8];
      C[nt] = __builtin_amdgcn_mfma_f32_16x16x32_bf16(afr[kt], bfr, C[nt], 0, 0, 0);
    }
}

// Grid 256. Pack all weights -> bf16 MFMA-B-frag order; blocks<64 init h. (R2-exact)
__global__ __launch_bounds__(256) void k_init(
    const float* __restrict__ emb, const int* __restrict__ z,
    const float* __restrict__ gf, const float* __restrict__ Wt,
    const float* __restrict__ Wr1, const float* __restrict__ Wr2,
    const float* __restrict__ Wupd, const float* __restrict__ Wmix,
    const float* __restrict__ Wg1, const float* __restrict__ Wg2,
    float* __restrict__ h, unsigned short* __restrict__ Wpack) {
  __shared__ float tvec[HH];
  __shared__ int sz[NN];
  int b4 = blockIdx.x, tid = threadIdx.x;
  {
    int p2 = b4 * 256 + tid;
    int p = p2 * 2;
    int m = p >> 14;
    int j = p & 7;
    int q = (p >> 3) & 3;
    int n = (p >> 5) & 127;
    int kt = (p >> 12) & 3;
    int k = kt * 32 + q * 8 + j;
    const float* src;
    int base;
    if (m < 2) { src = Wr2; base = m * 16384; }
    else if (m < 4) { src = Wupd; base = (m - 2) * 16384; }
    else if (m < 6) { src = Wmix; base = (m - 4) * 16384; }
    else if (m == 6) { src = Wg1; base = 0; }
    else { src = Wg2; base = 0; }
    float v0 = src[base + k * 128 + n];
    float v1 = src[base + (k + 1) * 128 + n];
    *(unsigned*)&Wpack[p] = bf2(v0, v1);
  }
  if (tid < 32) {
    int e = b4 * 32 + tid;
    int l = e >> 12, p = e & 4095;
    int n = p >> 5, q = (p >> 3) & 3, j = p & 7;
    float val = (q == 0) ? Wr1[l * NBB * HH + j * HH + n] : 0.f;
    Wpack[WR1OFF + l * 4096 + p] = bf1(val);
  }
  if (b4 < 64) {
    int b = b4;
    if (tid < NN) sz[tid] = z[b * NN + tid];
    if (tid < HH) {
      float acc = 0.f;
#pragma unroll
      for (int k = 0; k < TT; ++k) acc += gf[b * TT + k] * Wt[k * HH + tid];
      tvec[tid] = acc;
    }
    __syncthreads();
    for (int i = tid; i < NN * HH; i += 256) {
      int n = i >> 7, c = i & 127;
      h[(size_t)b * NN * HH + i] = emb[sz[n] * HH + c] + tvec[c];
    }
  }
}

// Layer 0. Grid BB*16 = 1024, 4 receivers/block: 41984 B LDS -> 3 blocks/CU =
// 12 waves/CU resident. Single Stage-A phase covers all 4 receivers.
__global__ __launch_bounds__(256) void k_layer0(
    const float* __restrict__ pos, const float* __restrict__ hA,
    unsigned short* __restrict__ apout, const unsigned short* __restrict__ Wpack) {
  __shared__ __align__(16) unsigned short sh_S[NN][136];     // 17408 B
  __shared__ __align__(16) unsigned short sh_M0T[4][32][72]; // 18432 B
  __shared__ __align__(16) unsigned short sh_rbh[4][NN][8];  // 4096 B
  __shared__ __align__(16) unsigned short sh_ub[4][4][NN];   // 2048 B

  int blk = blockIdx.x;
  int b = blk >> 4, rp4 = blk & 15;
  int r0 = rp4 * 4;
  int tid = threadIdx.x;
  int w = tid >> 6, lane = tid & 63;
  int nlo = lane & 15, quad = lane >> 4;
  const short8 zero8 = {0, 0, 0, 0, 0, 0, 0, 0};

  f32x4 hbv[4][2];
#pragma unroll
  for (int mt = 0; mt < 4; ++mt)
#pragma unroll
    for (int nt = 0; nt < 2; ++nt)
#pragma unroll
      for (int reg = 0; reg < 4; ++reg)
        hbv[mt][nt][reg] =
            hA[((size_t)b * NN + mt * 16 + quad * 4 + reg) * HH + w * 32 + nt * 16 + nlo];

  const unsigned short* Wr1p = Wpack + WR1OFF;
  short8 bw[2];
#pragma unroll
  for (int nt = 0; nt < 2; ++nt)
    bw[nt] = *(const short8*)&Wr1p[((w * 32 + nt * 16 + nlo) * 4 + quad) * 8];
  const unsigned short* Bbase = Wpack;
  short8 bfr[4][2];
#pragma unroll
  for (int kt = 0; kt < 4; ++kt)
#pragma unroll
    for (int nt = 0; nt < 2; ++nt)
      bfr[kt][nt] = *(const short8*)&Bbase[((kt * 128 + w * 32 + nt * 16 + nlo) * 4 + quad) * 8];

  // ---- Stage A: all 4 receivers at once ----
  {
    int s = tid & 63;
    int ri4 = tid >> 6;
    int r = r0 + ri4;
    const float* pb = pos + b * NN * 3;
    float dx = pb[r * 3 + 0] - pb[s * 3 + 0];
    float dy = pb[r * 3 + 1] - pb[s * 3 + 1];
    float dz = pb[r * 3 + 2] - pb[s * 3 + 2];
    float rr = sqrtf(dx * dx + dy * dy + dz * dz + 1e-12f);
    float inv = __builtin_amdgcn_rcpf(rr);
    const float invAvg = 1.0f / 63.0f;
    float ia = inv * invAvg;
    sh_ub[ri4][0][s] = bf1(invAvg);
    sh_ub[ri4][1][s] = bf1(dx * ia);
    sh_ub[ri4][2][s] = bf1(dy * ia);
    sh_ub[ri4][3][s] = bf1(dz * ia);
    const float PI_OVER_5 = 0.628318530717958647692f;
    float fc = (s != r && rr < 5.0f) ? 0.5f * (__cosf(PI_OVER_5 * rr) + 1.0f) : 0.0f;
    float base = PI_OVER_5 * rr;
    float sc = inv * fc;
#pragma unroll
    for (int k0 = 0; k0 < 8; k0 += 4) {
      float v0 = __sinf((float)(k0 + 1) * base) * sc;
      float v1 = __sinf((float)(k0 + 2) * base) * sc;
      float v2 = __sinf((float)(k0 + 3) * base) * sc;
      float v3 = __sinf((float)(k0 + 4) * base) * sc;
      *(unsigned*)&sh_rbh[ri4][s][k0]     = bf2(v0, v1);
      *(unsigned*)&sh_rbh[ri4][s][k0 + 2] = bf2(v2, v3);
    }
  }
  __syncthreads();

#pragma unroll
  for (int rsel = 0; rsel < 4; ++rsel) {
    // ---- Stage B ----
#pragma unroll
    for (int mtp = 0; mtp < 2; ++mtp) {
      f32x4 Cs[2][2];
#pragma unroll
      for (int mi = 0; mi < 2; ++mi)
#pragma unroll
        for (int nt = 0; nt < 2; ++nt) Cs[mi][nt] = (f32x4){0.f, 0.f, 0.f, 0.f};
#pragma unroll
      for (int mi = 0; mi < 2; ++mi) {
        int mt = mtp * 2 + mi;
        short8 afr = (quad == 0) ? *(const short8*)&sh_rbh[rsel][mt * 16 + nlo][0] : zero8;
#pragma unroll
        for (int nt = 0; nt < 2; ++nt)
          Cs[mi][nt] = __builtin_amdgcn_mfma_f32_16x16x32_bf16(afr, bw[nt], Cs[mi][nt], 0, 0, 0);
      }
#pragma unroll
      for (int mi = 0; mi < 2; ++mi)
#pragma unroll
        for (int nt = 0; nt < 2; ++nt)
#pragma unroll
          for (int reg = 0; reg < 4; ++reg) {
            int s = (mtp * 2 + mi) * 16 + quad * 4 + reg;
            int c = w * 32 + nt * 16 + nlo;
            sh_S[s][c] = bf1(silu_f(Cs[mi][nt][reg]));
          }
    }
    __syncthreads();

    // ---- Main GEMM + M0T ----
#pragma unroll
    for (int mt = 0; mt < 4; ++mt) {
      short8 afr[4];
      int s_a = mt * 16 + nlo;
#pragma unroll
      for (int kt = 0; kt < 4; ++kt)
        afr[kt] = *(const short8*)&sh_S[s_a][kt * 32 + quad * 8];
#pragma unroll
      for (int nt = 0; nt < 2; ++nt) {
        f32x4 C = {0.f, 0.f, 0.f, 0.f};
#pragma unroll
        for (int kt = 0; kt < 4; ++kt)
          C = __builtin_amdgcn_mfma_f32_16x16x32_bf16(afr[kt], bfr[kt][nt], C, 0, 0, 0);
        f32x4 m0 = C * hbv[mt][nt];
        u32x2 pk;
        pk.x = bf2(m0[0], m0[1]);
        pk.y = bf2(m0[2], m0[3]);
        *(u32x2*)&sh_M0T[w][nt * 16 + nlo][mt * 16 + quad * 4] = pk;
      }
    }
    // ---- U-GEMM -> global planes 0-3 ----
    {
      short8 au[2];
#pragma unroll
      for (int kt = 0; kt < 2; ++kt)
        au[kt] = (nlo < 4) ? *(const short8*)&sh_ub[rsel][nlo][kt * 32 + quad * 8] : zero8;
      f32x4 Cu[2] = {{0, 0, 0, 0}, {0, 0, 0, 0}};
#pragma unroll
      for (int nt = 0; nt < 2; ++nt)
#pragma unroll
        for (int kt = 0; kt < 2; ++kt) {
          short8 bm = *(const short8*)&sh_M0T[w][nt * 16 + nlo][kt * 32 + quad * 8];
          Cu[nt] = __builtin_amdgcn_mfma_f32_16x16x32_bf16(au[kt], bm, Cu[nt], 0, 0, 0);
        }
      if (quad == 0) {
#pragma unroll
        for (int nt = 0; nt < 2; ++nt) {
          size_t base = (size_t)(b * NN + r0 + rsel) * HH + w * 32 + nt * 16 + nlo;
#pragma unroll
          for (int reg = 0; reg < 4; ++reg)
            apout[reg * PLANE + base] = bf1(Cu[nt][reg]);
        }
      }
    }
    if (rsel != 3) __syncthreads();
  }
}

// Fused layer-1 + update/readout. Grid 512: block blk = (b = blk>>3, u8 = blk&7)
// computes receivers [u8*8, u8*8+8) = rows [blk*8, blk*8+8), then updates/reads
// out those rows. Planes 4-7 stay in LDS (sh_a47); cross-block inputs (a0_l0,
// planes 0-3, hA) come from prior launches (launch-boundary coherent).
__global__ __launch_bounds__(256) void k_fused(
    const float* __restrict__ pos, const float* __restrict__ hA,
    unsigned short* __restrict__ apbf, const unsigned short* __restrict__ Wpack,
    const float* __restrict__ fs, float* __restrict__ out) {
  __shared__ __align__(16) unsigned char smem[50688];
  unsigned short (*sh_S)[136]      = (unsigned short (*)[136])smem;               // 17408 B
  unsigned short (*sh_M0T)[32][72] = (unsigned short (*)[32][72])(smem + 17408);  // 18432 B
  unsigned short (*sh_rbh)[NN][8]  = (unsigned short (*)[NN][8])(smem + 35840);   // 4096 B
  unsigned short (*sh_ub)[4][NN]   = (unsigned short (*)[4][NN])(smem + 39936);   // 2048 B
  unsigned short (*sh_a47)[8][136] = (unsigned short (*)[8][136])(smem + 41984);  // 8704 B

  int blk = blockIdx.x;
  int b = blk >> 3, u8 = blk & 7;
  int tid = threadIdx.x;
  int w = tid >> 6, lane = tid & 63;
  int nlo = lane & 15, quad = lane >> 4;
  const short8 zero8 = {0, 0, 0, 0, 0, 0, 0, 0};

  // ---- hbv: graph h in C-reg layout ----
  f32x4 hbv[4][2];
#pragma unroll
  for (int mt = 0; mt < 4; ++mt)
#pragma unroll
    for (int nt = 0; nt < 2; ++nt)
#pragma unroll
      for (int reg = 0; reg < 4; ++reg)
        hbv[mt][nt][reg] =
            hA[((size_t)b * NN + mt * 16 + quad * 4 + reg) * HH + w * 32 + nt * 16 + nlo];

  // ---- stage a0_l0 (prior launch) and apply hbv += a0_l0 @ Wupd0 ----
  for (int i = tid; i < NN * 64; i += 256) {
    int s = i >> 6, c2 = (i & 63) * 2;
    *(unsigned*)&sh_S[s][c2] =
        *(const unsigned*)&apbf[((size_t)b * NN + s) * HH + c2];
  }
  __syncthreads();
  {
    const unsigned short* Bu = Wpack + 2 * 16384;
#pragma unroll
    for (int mt = 0; mt < 4; ++mt) {
      short8 afr[4];
#pragma unroll
      for (int kt = 0; kt < 4; ++kt)
        afr[kt] = *(const short8*)&sh_S[mt * 16 + nlo][kt * 32 + quad * 8];
#pragma unroll
      for (int nt = 0; nt < 2; ++nt)
#pragma unroll
        for (int kt = 0; kt < 4; ++kt) {
          short8 bfr2 = *(const short8*)&Bu[((kt * 128 + w * 32 + nt * 16 + nlo) * 4 + quad) * 8];
          hbv[mt][nt] = __builtin_amdgcn_mfma_f32_16x16x32_bf16(afr[kt], bfr2, hbv[mt][nt], 0, 0, 0);
        }
    }
  }
  __syncthreads();   // sh_S reads done before Stage B overwrites

  // ---- layer-1 fragment hoists ----
  const unsigned short* Wr1p = Wpack + WR1OFF + 4096;
  short8 bw[2];
#pragma unroll
  for (int nt = 0; nt < 2; ++nt)
    bw[nt] = *(const short8*)&Wr1p[((w * 32 + nt * 16 + nlo) * 4 + quad) * 8];
  const unsigned short* Bbase = Wpack + 16384;
  short8 bfr[4][2];
#pragma unroll
  for (int kt = 0; kt < 4; ++kt)
#pragma unroll
    for (int nt = 0; nt < 2; ++nt)
      bfr[kt][nt] = *(const short8*)&Bbase[((kt * 128 + w * 32 + nt * 16 + nlo) * 4 + quad) * 8];

  for (int unit = 0; unit < 2; ++unit) {
    int r0 = u8 * 8 + unit * 4;

    // ---- Stage A: 4 receivers of this unit ----
    {
      int s = tid & 63;
      int ri4 = tid >> 6;
      int r = r0 + ri4;
      const float* pb = pos + b * NN * 3;
      float dx = pb[r * 3 + 0] - pb[s * 3 + 0];
      float dy = pb[r * 3 + 1] - pb[s * 3 + 1];
      float dz = pb[r * 3 + 2] - pb[s * 3 + 2];
      float rr = sqrtf(dx * dx + dy * dy + dz * dz + 1e-12f);
      float inv = __builtin_amdgcn_rcpf(rr);
      const float invAvg = 1.0f / 63.0f;
      float ia = inv * invAvg;
      sh_ub[ri4][0][s] = bf1(invAvg);
      sh_ub[ri4][1][s] = bf1(dx * ia);
      sh_ub[ri4][2][s] = bf1(dy * ia);
      sh_ub[ri4][3][s] = bf1(dz * ia);
      const float PI_OVER_5 = 0.628318530717958647692f;
      float fc = (s != r && rr < 5.0f) ? 0.5f * (__cosf(PI_OVER_5 * rr) + 1.0f) : 0.0f;
      float base = PI_OVER_5 * rr;
      float sc = inv * fc;
#pragma unroll
      for (int k0 = 0; k0 < 8; k0 += 4) {
        float v0 = __sinf((float)(k0 + 1) * base) * sc;
        float v1 = __sinf((float)(k0 + 2) * base) * sc;
        float v2 = __sinf((float)(k0 + 3) * base) * sc;
        float v3 = __sinf((float)(k0 + 4) * base) * sc;
        *(unsigned*)&sh_rbh[ri4][s][k0]     = bf2(v0, v1);
        *(unsigned*)&sh_rbh[ri4][s][k0 + 2] = bf2(v2, v3);
      }
    }
    __syncthreads();

#pragma unroll
    for (int rsel = 0; rsel < 4; ++rsel) {
      int lr = unit * 4 + rsel;   // local row 0..7
      // ---- Stage B ----
#pragma unroll
      for (int mtp = 0; mtp < 2; ++mtp) {
        f32x4 Cs[2][2];
#pragma unroll
        for (int mi = 0; mi < 2; ++mi)
#pragma unroll
          for (int nt = 0; nt < 2; ++nt) Cs[mi][nt] = (f32x4){0.f, 0.f, 0.f, 0.f};
#pragma unroll
        for (int mi = 0; mi < 2; ++mi) {
          int mt = mtp * 2 + mi;
          short8 afr = (quad == 0) ? *(const short8*)&sh_rbh[rsel][mt * 16 + nlo][0] : zero8;
#pragma unroll
          for (int nt = 0; nt < 2; ++nt)
            Cs[mi][nt] = __builtin_amdgcn_mfma_f32_16x16x32_bf16(afr, bw[nt], Cs[mi][nt], 0, 0, 0);
        }
#pragma unroll
        for (int mi = 0; mi < 2; ++mi)
#pragma unroll
          for (int nt = 0; nt < 2; ++nt)
#pragma unroll
            for (int reg = 0; reg < 4; ++reg) {
              int s = (mtp * 2 + mi) * 16 + quad * 4 + reg;
              int c = w * 32 + nt * 16 + nlo;
              sh_S[s][c] = bf1(silu_f(Cs[mi][nt][reg]));
            }
      }
      __syncthreads();

      // ---- Main GEMM + M0T ----
#pragma unroll
      for (int mt = 0; mt < 4; ++mt) {
        short8 afr[4];
        int s_a = mt * 16 + nlo;
#pragma unroll
        for (int kt = 0; kt < 4; ++kt)
          afr[kt] = *(const short8*)&sh_S[s_a][kt * 32 + quad * 8];
#pragma unroll
        for (int nt = 0; nt < 2; ++nt) {
          f32x4 C = {0.f, 0.f, 0.f, 0.f};
#pragma unroll
          for (int kt = 0; kt < 4; ++kt)
            C = __builtin_amdgcn_mfma_f32_16x16x32_bf16(afr[kt], bfr[kt][nt], C, 0, 0, 0);
          f32x4 m0 = C * hbv[mt][nt];
          u32x2 pk;
          pk.x = bf2(m0[0], m0[1]);
          pk.y = bf2(m0[2], m0[3]);
          *(u32x2*)&sh_M0T[w][nt * 16 + nlo][mt * 16 + quad * 4] = pk;
        }
      }
      // ---- U-GEMM -> sh_a47 (LDS only, no global) ----
      {
        short8 au[2];
#pragma unroll
        for (int kt = 0; kt < 2; ++kt)
          au[kt] = (nlo < 4) ? *(const short8*)&sh_ub[rsel][nlo][kt * 32 + quad * 8] : zero8;
        f32x4 Cu[2] = {{0, 0, 0, 0}, {0, 0, 0, 0}};
#pragma unroll
        for (int nt = 0; nt < 2; ++nt)
#pragma unroll
          for (int kt = 0; kt < 2; ++kt) {
            short8 bm = *(const short8*)&sh_M0T[w][nt * 16 + nlo][kt * 32 + quad * 8];
            Cu[nt] = __builtin_amdgcn_mfma_f32_16x16x32_bf16(au[kt], bm, Cu[nt], 0, 0, 0);
          }
        if (quad == 0) {
#pragma unroll
          for (int nt = 0; nt < 2; ++nt) {
            int c = w * 32 + nt * 16 + nlo;
#pragma unroll
            for (int reg = 0; reg < 4; ++reg)
              sh_a47[reg][lr][c] = bf1(Cu[nt][reg]);
          }
        }
      }
      __syncthreads();   // sh_S/rbh/ub safe to overwrite; a47 visible later
    }
  }

  // ---- update + readout for rows [blk*8, blk*8+8) ----
  {
    unsigned short (*sh_a03)[8][136] = (unsigned short (*)[8][136])smem;          // 8704 B
    unsigned short (*sh_h)[136]      = (unsigned short (*)[136])(smem + 8704);    // 2176 B
    float (*red)[8][3]               = (float (*)[8][3])(smem + 8704 + 2176);     // 384 B
    int row0 = blk * 8;
    for (int i = tid; i < 4 * 8 * 64; i += 256) {
      int p = i >> 9, rr = (i >> 6) & 7, c2 = (i & 63) * 2;
      *(unsigned*)&sh_a03[p][rr][c2] =
          *(const unsigned*)&apbf[p * PLANE + (size_t)(row0 + rr) * HH + c2];
    }
    f32x4 Ch[2];
#pragma unroll
    for (int nt = 0; nt < 2; ++nt)
#pragma unroll
      for (int reg = 0; reg < 4; ++reg)
        Ch[nt][reg] = (quad < 2)
            ? hA[(size_t)(row0 + quad * 4 + reg) * HH + w * 32 + nt * 16 + nlo] : 0.f;
    __syncthreads();
    gemm8(sh_a03[0], Wpack + 2 * 16384, w, nlo, quad, Ch);   // + a0l0@Wupd0
    gemm8(sh_a47[0], Wpack + 3 * 16384, w, nlo, quad, Ch);   // + a0l1@Wupd1
    f32x4 Cx[2] = {{0,0,0,0},{0,0,0,0}};
    f32x4 Cy[2] = {{0,0,0,0},{0,0,0,0}};
    f32x4 Cz[2] = {{0,0,0,0},{0,0,0,0}};
    gemm8(sh_a03[1], Wpack + 4 * 16384, w, nlo, quad, Cx);
    gemm8(sh_a47[1], Wpack + 5 * 16384, w, nlo, quad, Cx);
    gemm8(sh_a03[2], Wpack + 4 * 16384, w, nlo, quad, Cy);
    gemm8(sh_a47[2], Wpack + 5 * 16384, w, nlo, quad, Cy);
    gemm8(sh_a03[3], Wpack + 4 * 16384, w, nlo, quad, Cz);
    gemm8(sh_a47[3], Wpack + 5 * 16384, w, nlo, quad, Cz);
    if (quad < 2) {
#pragma unroll
      for (int nt = 0; nt < 2; ++nt)
#pragma unroll
        for (int reg = 0; reg < 4; ++reg)
          sh_h[quad * 4 + reg][w * 32 + nt * 16 + nlo] = bf1(Ch[nt][reg]);
    }
    __syncthreads();   // sh_h ready; sh_a03[0] free to alias
    unsigned short (*sh_q)[136] = sh_a03[0];
    f32x4 Cq[2] = {{0,0,0,0},{0,0,0,0}};
    gemm8(sh_h, Wpack + 6 * 16384, w, nlo, quad, Cq);
    if (quad < 2) {
#pragma unroll
      for (int nt = 0; nt < 2; ++nt)
#pragma unroll
        for (int reg = 0; reg < 4; ++reg)
          sh_q[quad * 4 + reg][w * 32 + nt * 16 + nlo] = bf1(silu_f(Cq[nt][reg]));
    }
    __syncthreads();
    f32x4 Cg[2] = {{0,0,0,0},{0,0,0,0}};
    gemm8(sh_q, Wpack + 7 * 16384, w, nlo, quad, Cg);
    float pr[3][4];
#pragma unroll
    for (int d = 0; d < 3; ++d)
#pragma unroll
      for (int reg = 0; reg < 4; ++reg) pr[d][reg] = 0.f;
#pragma unroll
    for (int nt = 0; nt < 2; ++nt)
#pragma unroll
      for (int reg = 0; reg < 4; ++reg) {
        float gv = Cg[nt][reg];
        pr[0][reg] += gv * Cx[nt][reg];
        pr[1][reg] += gv * Cy[nt][reg];
        pr[2][reg] += gv * Cz[nt][reg];
      }
#pragma unroll
    for (int off = 1; off < 16; off <<= 1)
#pragma unroll
      for (int d = 0; d < 3; ++d)
#pragma unroll
        for (int reg = 0; reg < 4; ++reg)
          pr[d][reg] += __shfl_xor(pr[d][reg], off);
    if (nlo == 0 && quad < 2) {
#pragma unroll
      for (int d = 0; d < 3; ++d)
#pragma unroll
        for (int reg = 0; reg < 4; ++reg)
          red[w][quad * 4 + reg][d] = pr[d][reg];
    }
    __syncthreads();
    if (tid < 24) {
      int row = tid / 3, d = tid % 3;
      float s = red[0][row][d] + red[1][row][d] + red[2][row][d] + red[3][row][d];
      out[(size_t)(row0 + row) * 3 + d] = s * fs[0];
    }
  }
}

extern "C" void kernel_launch(void* const* d_in, const int* in_sizes, int n_in,
                              void* d_out, int out_size, void* d_ws, size_t ws_size,
                              hipStream_t stream) {
  const float* pos  = (const float*)d_in[0];
  const int*   z    = (const int*)d_in[1];
  const float* gf   = (const float*)d_in[2];
  const float* emb  = (const float*)d_in[3];
  const float* Wt   = (const float*)d_in[4];
  const float* Wr1  = (const float*)d_in[5];
  const float* Wr2  = (const float*)d_in[6];
  const float* Wupd = (const float*)d_in[7];
  const float* Wmix = (const float*)d_in[8];
  const float* Wg1  = (const float*)d_in[9];
  const float* Wg2  = (const float*)d_in[10];
  const float* fs   = (const float*)d_in[11];
  float* out = (float*)d_out;

  float* ws = (float*)d_ws;
  float* hA = ws;                                         // 2 MB
  unsigned short* apbf = (unsigned short*)(ws + PLANE);   // bf16 planes (0-3 used)
  unsigned short* Wpack = (unsigned short*)(ws + 5 * PLANE);  // 272 KB

  k_init<<<dim3(256), dim3(256), 0, stream>>>(emb, z, gf, Wt, Wr1, Wr2, Wupd,
                                              Wmix, Wg1, Wg2, hA, Wpack);
  k_layer0<<<dim3(BB * 16), dim3(256), 0, stream>>>(pos, hA, apbf, Wpack);
  k_fused<<<dim3(512), dim3(256), 0, stream>>>(pos, hA, apbf, Wpack, fs, out);
}

// Round 15
// 137.651 us; speedup vs baseline: 1.0406x; 1.0068x over previous
//
#include <hip/hip_runtime.h>
#include <math.h>

#define NN 64      // nodes per graph
#define HH 128     // hidden channels
#define NBB 8      // bessel basis
#define TT 32      // time embedding dim
#define BB 64      // batch
#define NROW (BB * NN)        // 4096 total rows
#define PLANE ((size_t)NROW * HH)   // 524288
#define WR1OFF (8 * 16384)    // Wr1 B-frag slabs in Wpack (2 x 4096)

typedef __attribute__((ext_vector_type(8))) short short8;
typedef __attribute__((ext_vector_type(4))) float f32x4;
typedef __attribute__((ext_vector_type(2))) unsigned int u32x2;

__device__ __forceinline__ float silu_f(float x) {
  return x * __builtin_amdgcn_rcpf(1.0f + __expf(-x));
}

__device__ __forceinline__ unsigned short bf1(float x) {
  __bf16 h = (__bf16)x;
  return *(unsigned short*)&h;
}
__device__ __forceinline__ unsigned bf2(float lo, float hi) {
  return (unsigned)bf1(lo) | ((unsigned)bf1(hi) << 16);
}

// 8-row MFMA GEMM tile: A rows 8..15 zero. C map: row=quad*4+reg (<8), col=w*32+nt*16+nlo.
__device__ __forceinline__ void gemm8(
    const unsigned short (*sA)[136], const unsigned short* __restrict__ Bp,
    int w, int nlo, int quad, f32x4 C[2]) {
  const short8 z8 = {0, 0, 0, 0, 0, 0, 0, 0};
  short8 afr[4];
#pragma unroll
  for (int kt = 0; kt < 4; ++kt)
    afr[kt] = (nlo < 8) ? *(const short8*)&sA[nlo][kt * 32 + quad * 8] : z8;
#pragma unroll
  for (int nt = 0; nt < 2; ++nt)
#pragma unroll
    for (int kt = 0; kt < 4; ++kt) {
      short8 bfr = *(const short8*)&Bp[((kt * 128 + w * 32 + nt * 16 + nlo) * 4 + quad) * 8];
      C[nt] = __builtin_amdgcn_mfma_f32_16x16x32_bf16(afr[kt], bfr, C[nt], 0, 0, 0);
    }
}

// Grid 256. Pack all weights -> bf16 MFMA-B-frag order. h-init spread across ALL
// 256 blocks (4 blocks/graph x 16 rows) -- removes the blocks<64 straggler tail.
__global__ __launch_bounds__(256) void k_init(
    const float* __restrict__ emb, const int* __restrict__ z,
    const float* __restrict__ gf, const float* __restrict__ Wt,
    const float* __restrict__ Wr1, const float* __restrict__ Wr2,
    const float* __restrict__ Wupd, const float* __restrict__ Wmix,
    const float* __restrict__ Wg1, const float* __restrict__ Wg2,
    float* __restrict__ h, unsigned short* __restrict__ Wpack) {
  __shared__ float tvec[HH];
  __shared__ int sz[16];
  int b4 = blockIdx.x, tid = threadIdx.x;
  {
    int p2 = b4 * 256 + tid;
    int p = p2 * 2;
    int m = p >> 14;
    int j = p & 7;
    int q = (p >> 3) & 3;
    int n = (p >> 5) & 127;
    int kt = (p >> 12) & 3;
    int k = kt * 32 + q * 8 + j;
    const float* src;
    int base;
    if (m < 2) { src = Wr2; base = m * 16384; }
    else if (m < 4) { src = Wupd; base = (m - 2) * 16384; }
    else if (m < 6) { src = Wmix; base = (m - 4) * 16384; }
    else if (m == 6) { src = Wg1; base = 0; }
    else { src = Wg2; base = 0; }
    float v0 = src[base + k * 128 + n];
    float v1 = src[base + (k + 1) * 128 + n];
    *(unsigned*)&Wpack[p] = bf2(v0, v1);
  }
  if (tid < 32) {
    int e = b4 * 32 + tid;
    int l = e >> 12, p = e & 4095;
    int n = p >> 5, q = (p >> 3) & 3, j = p & 7;
    float val = (q == 0) ? Wr1[l * NBB * HH + j * HH + n] : 0.f;
    Wpack[WR1OFF + l * 4096 + p] = bf1(val);
  }
  {
    int b = b4 >> 2;               // graph
    int n0 = (b4 & 3) * 16;        // this block's 16 rows
    if (tid < 16) sz[tid] = z[b * NN + n0 + tid];
    if (tid < HH) {
      float acc = 0.f;
#pragma unroll
      for (int k = 0; k < TT; ++k) acc += gf[b * TT + k] * Wt[k * HH + tid];
      tvec[tid] = acc;
    }
    __syncthreads();
    for (int i = tid; i < 16 * HH; i += 256) {
      int n = i >> 7, c = i & 127;
      h[(size_t)b * NN * HH + (n0 + n) * HH + c] = emb[sz[n] * HH + c] + tvec[c];
    }
  }
}

// Layer 0. Grid BB*16 = 1024, 4 receivers/block: 41984 B LDS -> 3 blocks/CU =
// 12 waves/CU resident. Single Stage-A phase covers all 4 receivers.
__global__ __launch_bounds__(256) void k_layer0(
    const float* __restrict__ pos, const float* __restrict__ hA,
    unsigned short* __restrict__ apout, const unsigned short* __restrict__ Wpack) {
  __shared__ __align__(16) unsigned short sh_S[NN][136];     // 17408 B
  __shared__ __align__(16) unsigned short sh_M0T[4][32][72]; // 18432 B
  __shared__ __align__(16) unsigned short sh_rbh[4][NN][8];  // 4096 B
  __shared__ __align__(16) unsigned short sh_ub[4][4][NN];   // 2048 B

  int blk = blockIdx.x;
  int b = blk >> 4, rp4 = blk & 15;
  int r0 = rp4 * 4;
  int tid = threadIdx.x;
  int w = tid >> 6, lane = tid & 63;
  int nlo = lane & 15, quad = lane >> 4;
  const short8 zero8 = {0, 0, 0, 0, 0, 0, 0, 0};

  f32x4 hbv[4][2];
#pragma unroll
  for (int mt = 0; mt < 4; ++mt)
#pragma unroll
    for (int nt = 0; nt < 2; ++nt)
#pragma unroll
      for (int reg = 0; reg < 4; ++reg)
        hbv[mt][nt][reg] =
            hA[((size_t)b * NN + mt * 16 + quad * 4 + reg) * HH + w * 32 + nt * 16 + nlo];

  const unsigned short* Wr1p = Wpack + WR1OFF;
  short8 bw[2];
#pragma unroll
  for (int nt = 0; nt < 2; ++nt)
    bw[nt] = *(const short8*)&Wr1p[((w * 32 + nt * 16 + nlo) * 4 + quad) * 8];
  const unsigned short* Bbase = Wpack;
  short8 bfr[4][2];
#pragma unroll
  for (int kt = 0; kt < 4; ++kt)
#pragma unroll
    for (int nt = 0; nt < 2; ++nt)
      bfr[kt][nt] = *(const short8*)&Bbase[((kt * 128 + w * 32 + nt * 16 + nlo) * 4 + quad) * 8];

  // ---- Stage A: all 4 receivers at once ----
  {
    int s = tid & 63;
    int ri4 = tid >> 6;
    int r = r0 + ri4;
    const float* pb = pos + b * NN * 3;
    float dx = pb[r * 3 + 0] - pb[s * 3 + 0];
    float dy = pb[r * 3 + 1] - pb[s * 3 + 1];
    float dz = pb[r * 3 + 2] - pb[s * 3 + 2];
    float rr = sqrtf(dx * dx + dy * dy + dz * dz + 1e-12f);
    float inv = __builtin_amdgcn_rcpf(rr);
    const float invAvg = 1.0f / 63.0f;
    float ia = inv * invAvg;
    sh_ub[ri4][0][s] = bf1(invAvg);
    sh_ub[ri4][1][s] = bf1(dx * ia);
    sh_ub[ri4][2][s] = bf1(dy * ia);
    sh_ub[ri4][3][s] = bf1(dz * ia);
    const float PI_OVER_5 = 0.628318530717958647692f;
    float fc = (s != r && rr < 5.0f) ? 0.5f * (__cosf(PI_OVER_5 * rr) + 1.0f) : 0.0f;
    float base = PI_OVER_5 * rr;
    float sc = inv * fc;
#pragma unroll
    for (int k0 = 0; k0 < 8; k0 += 4) {
      float v0 = __sinf((float)(k0 + 1) * base) * sc;
      float v1 = __sinf((float)(k0 + 2) * base) * sc;
      float v2 = __sinf((float)(k0 + 3) * base) * sc;
      float v3 = __sinf((float)(k0 + 4) * base) * sc;
      *(unsigned*)&sh_rbh[ri4][s][k0]     = bf2(v0, v1);
      *(unsigned*)&sh_rbh[ri4][s][k0 + 2] = bf2(v2, v3);
    }
  }
  __syncthreads();

#pragma unroll
  for (int rsel = 0; rsel < 4; ++rsel) {
    // ---- Stage B ----
#pragma unroll
    for (int mtp = 0; mtp < 2; ++mtp) {
      f32x4 Cs[2][2];
#pragma unroll
      for (int mi = 0; mi < 2; ++mi)
#pragma unroll
        for (int nt = 0; nt < 2; ++nt) Cs[mi][nt] = (f32x4){0.f, 0.f, 0.f, 0.f};
#pragma unroll
      for (int mi = 0; mi < 2; ++mi) {
        int mt = mtp * 2 + mi;
        short8 afr = (quad == 0) ? *(const short8*)&sh_rbh[rsel][mt * 16 + nlo][0] : zero8;
#pragma unroll
        for (int nt = 0; nt < 2; ++nt)
          Cs[mi][nt] = __builtin_amdgcn_mfma_f32_16x16x32_bf16(afr, bw[nt], Cs[mi][nt], 0, 0, 0);
      }
#pragma unroll
      for (int mi = 0; mi < 2; ++mi)
#pragma unroll
        for (int nt = 0; nt < 2; ++nt)
#pragma unroll
          for (int reg = 0; reg < 4; ++reg) {
            int s = (mtp * 2 + mi) * 16 + quad * 4 + reg;
            int c = w * 32 + nt * 16 + nlo;
            sh_S[s][c] = bf1(silu_f(Cs[mi][nt][reg]));
          }
    }
    __syncthreads();

    // ---- Main GEMM + M0T ----
#pragma unroll
    for (int mt = 0; mt < 4; ++mt) {
      short8 afr[4];
      int s_a = mt * 16 + nlo;
#pragma unroll
      for (int kt = 0; kt < 4; ++kt)
        afr[kt] = *(const short8*)&sh_S[s_a][kt * 32 + quad * 8];
#pragma unroll
      for (int nt = 0; nt < 2; ++nt) {
        f32x4 C = {0.f, 0.f, 0.f, 0.f};
#pragma unroll
        for (int kt = 0; kt < 4; ++kt)
          C = __builtin_amdgcn_mfma_f32_16x16x32_bf16(afr[kt], bfr[kt][nt], C, 0, 0, 0);
        f32x4 m0 = C * hbv[mt][nt];
        u32x2 pk;
        pk.x = bf2(m0[0], m0[1]);
        pk.y = bf2(m0[2], m0[3]);
        *(u32x2*)&sh_M0T[w][nt * 16 + nlo][mt * 16 + quad * 4] = pk;
      }
    }
    // ---- U-GEMM -> global planes 0-3 ----
    {
      short8 au[2];
#pragma unroll
      for (int kt = 0; kt < 2; ++kt)
        au[kt] = (nlo < 4) ? *(const short8*)&sh_ub[rsel][nlo][kt * 32 + quad * 8] : zero8;
      f32x4 Cu[2] = {{0, 0, 0, 0}, {0, 0, 0, 0}};
#pragma unroll
      for (int nt = 0; nt < 2; ++nt)
#pragma unroll
        for (int kt = 0; kt < 2; ++kt) {
          short8 bm = *(const short8*)&sh_M0T[w][nt * 16 + nlo][kt * 32 + quad * 8];
          Cu[nt] = __builtin_amdgcn_mfma_f32_16x16x32_bf16(au[kt], bm, Cu[nt], 0, 0, 0);
        }
      if (quad == 0) {
#pragma unroll
        for (int nt = 0; nt < 2; ++nt) {
          size_t base = (size_t)(b * NN + r0 + rsel) * HH + w * 32 + nt * 16 + nlo;
#pragma unroll
          for (int reg = 0; reg < 4; ++reg)
            apout[reg * PLANE + base] = bf1(Cu[nt][reg]);
        }
      }
    }
    if (rsel != 3) __syncthreads();
  }
}

// Fused layer-1 + update/readout. Grid 512: block blk = (b = blk>>3, u8 = blk&7)
// computes receivers [u8*8, u8*8+8) = rows [blk*8, blk*8+8), then updates/reads
// out those rows. Planes 4-7 stay in LDS (sh_a47); cross-block inputs (a0_l0,
// planes 0-3, hA) come from prior launches (launch-boundary coherent).
__global__ __launch_bounds__(256) void k_fused(
    const float* __restrict__ pos, const float* __restrict__ hA,
    unsigned short* __restrict__ apbf, const unsigned short* __restrict__ Wpack,
    const float* __restrict__ fs, float* __restrict__ out) {
  __shared__ __align__(16) unsigned char smem[50688];
  unsigned short (*sh_S)[136]      = (unsigned short (*)[136])smem;               // 17408 B
  unsigned short (*sh_M0T)[32][72] = (unsigned short (*)[32][72])(smem + 17408);  // 18432 B
  unsigned short (*sh_rbh)[NN][8]  = (unsigned short (*)[NN][8])(smem + 35840);   // 4096 B
  unsigned short (*sh_ub)[4][NN]   = (unsigned short (*)[4][NN])(smem + 39936);   // 2048 B
  unsigned short (*sh_a47)[8][136] = (unsigned short (*)[8][136])(smem + 41984);  // 8704 B

  int blk = blockIdx.x;
  int b = blk >> 3, u8 = blk & 7;
  int tid = threadIdx.x;
  int w = tid >> 6, lane = tid & 63;
  int nlo = lane & 15, quad = lane >> 4;
  const short8 zero8 = {0, 0, 0, 0, 0, 0, 0, 0};

  // ---- hbv: graph h in C-reg layout ----
  f32x4 hbv[4][2];
#pragma unroll
  for (int mt = 0; mt < 4; ++mt)
#pragma unroll
    for (int nt = 0; nt < 2; ++nt)
#pragma unroll
      for (int reg = 0; reg < 4; ++reg)
        hbv[mt][nt][reg] =
            hA[((size_t)b * NN + mt * 16 + quad * 4 + reg) * HH + w * 32 + nt * 16 + nlo];

  // ---- stage a0_l0 (prior launch) and apply hbv += a0_l0 @ Wupd0 ----
  for (int i = tid; i < NN * 64; i += 256) {
    int s = i >> 6, c2 = (i & 63) * 2;
    *(unsigned*)&sh_S[s][c2] =
        *(const unsigned*)&apbf[((size_t)b * NN + s) * HH + c2];
  }
  __syncthreads();
  {
    const unsigned short* Bu = Wpack + 2 * 16384;
#pragma unroll
    for (int mt = 0; mt < 4; ++mt) {
      short8 afr[4];
#pragma unroll
      for (int kt = 0; kt < 4; ++kt)
        afr[kt] = *(const short8*)&sh_S[mt * 16 + nlo][kt * 32 + quad * 8];
#pragma unroll
      for (int nt = 0; nt < 2; ++nt)
#pragma unroll
        for (int kt = 0; kt < 4; ++kt) {
          short8 bfr2 = *(const short8*)&Bu[((kt * 128 + w * 32 + nt * 16 + nlo) * 4 + quad) * 8];
          hbv[mt][nt] = __builtin_amdgcn_mfma_f32_16x16x32_bf16(afr[kt], bfr2, hbv[mt][nt], 0, 0, 0);
        }
    }
  }
  __syncthreads();   // sh_S reads done before Stage B overwrites

  // ---- layer-1 fragment hoists ----
  const unsigned short* Wr1p = Wpack + WR1OFF + 4096;
  short8 bw[2];
#pragma unroll
  for (int nt = 0; nt < 2; ++nt)
    bw[nt] = *(const short8*)&Wr1p[((w * 32 + nt * 16 + nlo) * 4 + quad) * 8];
  const unsigned short* Bbase = Wpack + 16384;
  short8 bfr[4][2];
#pragma unroll
  for (int kt = 0; kt < 4; ++kt)
#pragma unroll
    for (int nt = 0; nt < 2; ++nt)
      bfr[kt][nt] = *(const short8*)&Bbase[((kt * 128 + w * 32 + nt * 16 + nlo) * 4 + quad) * 8];

  for (int unit = 0; unit < 2; ++unit) {
    int r0 = u8 * 8 + unit * 4;

    // ---- Stage A: 4 receivers of this unit ----
    {
      int s = tid & 63;
      int ri4 = tid >> 6;
      int r = r0 + ri4;
      const float* pb = pos + b * NN * 3;
      float dx = pb[r * 3 + 0] - pb[s * 3 + 0];
      float dy = pb[r * 3 + 1] - pb[s * 3 + 1];
      float dz = pb[r * 3 + 2] - pb[s * 3 + 2];
      float rr = sqrtf(dx * dx + dy * dy + dz * dz + 1e-12f);
      float inv = __builtin_amdgcn_rcpf(rr);
      const float invAvg = 1.0f / 63.0f;
      float ia = inv * invAvg;
      sh_ub[ri4][0][s] = bf1(invAvg);
      sh_ub[ri4][1][s] = bf1(dx * ia);
      sh_ub[ri4][2][s] = bf1(dy * ia);
      sh_ub[ri4][3][s] = bf1(dz * ia);
      const float PI_OVER_5 = 0.628318530717958647692f;
      float fc = (s != r && rr < 5.0f) ? 0.5f * (__cosf(PI_OVER_5 * rr) + 1.0f) : 0.0f;
      float base = PI_OVER_5 * rr;
      float sc = inv * fc;
#pragma unroll
      for (int k0 = 0; k0 < 8; k0 += 4) {
        float v0 = __sinf((float)(k0 + 1) * base) * sc;
        float v1 = __sinf((float)(k0 + 2) * base) * sc;
        float v2 = __sinf((float)(k0 + 3) * base) * sc;
        float v3 = __sinf((float)(k0 + 4) * base) * sc;
        *(unsigned*)&sh_rbh[ri4][s][k0]     = bf2(v0, v1);
        *(unsigned*)&sh_rbh[ri4][s][k0 + 2] = bf2(v2, v3);
      }
    }
    __syncthreads();

#pragma unroll
    for (int rsel = 0; rsel < 4; ++rsel) {
      int lr = unit * 4 + rsel;   // local row 0..7
      // ---- Stage B ----
#pragma unroll
      for (int mtp = 0; mtp < 2; ++mtp) {
        f32x4 Cs[2][2];
#pragma unroll
        for (int mi = 0; mi < 2; ++mi)
#pragma unroll
          for (int nt = 0; nt < 2; ++nt) Cs[mi][nt] = (f32x4){0.f, 0.f, 0.f, 0.f};
#pragma unroll
        for (int mi = 0; mi < 2; ++mi) {
          int mt = mtp * 2 + mi;
          short8 afr = (quad == 0) ? *(const short8*)&sh_rbh[rsel][mt * 16 + nlo][0] : zero8;
#pragma unroll
          for (int nt = 0; nt < 2; ++nt)
            Cs[mi][nt] = __builtin_amdgcn_mfma_f32_16x16x32_bf16(afr, bw[nt], Cs[mi][nt], 0, 0, 0);
        }
#pragma unroll
        for (int mi = 0; mi < 2; ++mi)
#pragma unroll
          for (int nt = 0; nt < 2; ++nt)
#pragma unroll
            for (int reg = 0; reg < 4; ++reg) {
              int s = (mtp * 2 + mi) * 16 + quad * 4 + reg;
              int c = w * 32 + nt * 16 + nlo;
              sh_S[s][c] = bf1(silu_f(Cs[mi][nt][reg]));
            }
      }
      __syncthreads();

      // ---- Main GEMM + M0T ----
#pragma unroll
      for (int mt = 0; mt < 4; ++mt) {
        short8 afr[4];
        int s_a = mt * 16 + nlo;
#pragma unroll
        for (int kt = 0; kt < 4; ++kt)
          afr[kt] = *(const short8*)&sh_S[s_a][kt * 32 + quad * 8];
#pragma unroll
        for (int nt = 0; nt < 2; ++nt) {
          f32x4 C = {0.f, 0.f, 0.f, 0.f};
#pragma unroll
          for (int kt = 0; kt < 4; ++kt)
            C = __builtin_amdgcn_mfma_f32_16x16x32_bf16(afr[kt], bfr[kt][nt], C, 0, 0, 0);
          f32x4 m0 = C * hbv[mt][nt];
          u32x2 pk;
          pk.x = bf2(m0[0], m0[1]);
          pk.y = bf2(m0[2], m0[3]);
          *(u32x2*)&sh_M0T[w][nt * 16 + nlo][mt * 16 + quad * 4] = pk;
        }
      }
      // ---- U-GEMM -> sh_a47 (LDS only, no global) ----
      {
        short8 au[2];
#pragma unroll
        for (int kt = 0; kt < 2; ++kt)
          au[kt] = (nlo < 4) ? *(const short8*)&sh_ub[rsel][nlo][kt * 32 + quad * 8] : zero8;
        f32x4 Cu[2] = {{0, 0, 0, 0}, {0, 0, 0, 0}};
#pragma unroll
        for (int nt = 0; nt < 2; ++nt)
#pragma unroll
          for (int kt = 0; kt < 2; ++kt) {
            short8 bm = *(const short8*)&sh_M0T[w][nt * 16 + nlo][kt * 32 + quad * 8];
            Cu[nt] = __builtin_amdgcn_mfma_f32_16x16x32_bf16(au[kt], bm, Cu[nt], 0, 0, 0);
          }
        if (quad == 0) {
#pragma unroll
          for (int nt = 0; nt < 2; ++nt) {
            int c = w * 32 + nt * 16 + nlo;
#pragma unroll
            for (int reg = 0; reg < 4; ++reg)
              sh_a47[reg][lr][c] = bf1(Cu[nt][reg]);
          }
        }
      }
      __syncthreads();   // sh_S/rbh/ub safe to overwrite; a47 visible later
    }
  }

  // ---- update + readout for rows [blk*8, blk*8+8) ----
  {
    unsigned short (*sh_a03)[8][136] = (unsigned short (*)[8][136])smem;          // 8704 B
    unsigned short (*sh_h)[136]      = (unsigned short (*)[136])(smem + 8704);    // 2176 B
    float (*red)[8][3]               = (float (*)[8][3])(smem + 8704 + 2176);     // 384 B
    int row0 = blk * 8;
    for (int i = tid; i < 4 * 8 * 64; i += 256) {
      int p = i >> 9, rr = (i >> 6) & 7, c2 = (i & 63) * 2;
      *(unsigned*)&sh_a03[p][rr][c2] =
          *(const unsigned*)&apbf[p * PLANE + (size_t)(row0 + rr) * HH + c2];
    }
    f32x4 Ch[2];
#pragma unroll
    for (int nt = 0; nt < 2; ++nt)
#pragma unroll
      for (int reg = 0; reg < 4; ++reg)
        Ch[nt][reg] = (quad < 2)
            ? hA[(size_t)(row0 + quad * 4 + reg) * HH + w * 32 + nt * 16 + nlo] : 0.f;
    __syncthreads();
    gemm8(sh_a03[0], Wpack + 2 * 16384, w, nlo, quad, Ch);   // + a0l0@Wupd0
    gemm8(sh_a47[0], Wpack + 3 * 16384, w, nlo, quad, Ch);   // + a0l1@Wupd1
    f32x4 Cx[2] = {{0,0,0,0},{0,0,0,0}};
    f32x4 Cy[2] = {{0,0,0,0},{0,0,0,0}};
    f32x4 Cz[2] = {{0,0,0,0},{0,0,0,0}};
    gemm8(sh_a03[1], Wpack + 4 * 16384, w, nlo, quad, Cx);
    gemm8(sh_a47[1], Wpack + 5 * 16384, w, nlo, quad, Cx);
    gemm8(sh_a03[2], Wpack + 4 * 16384, w, nlo, quad, Cy);
    gemm8(sh_a47[2], Wpack + 5 * 16384, w, nlo, quad, Cy);
    gemm8(sh_a03[3], Wpack + 4 * 16384, w, nlo, quad, Cz);
    gemm8(sh_a47[3], Wpack + 5 * 16384, w, nlo, quad, Cz);
    if (quad < 2) {
#pragma unroll
      for (int nt = 0; nt < 2; ++nt)
#pragma unroll
        for (int reg = 0; reg < 4; ++reg)
          sh_h[quad * 4 + reg][w * 32 + nt * 16 + nlo] = bf1(Ch[nt][reg]);
    }
    __syncthreads();   // sh_h ready; sh_a03[0] free to alias
    unsigned short (*sh_q)[136] = sh_a03[0];
    f32x4 Cq[2] = {{0,0,0,0},{0,0,0,0}};
    gemm8(sh_h, Wpack + 6 * 16384, w, nlo, quad, Cq);
    if (quad < 2) {
#pragma unroll
      for (int nt = 0; nt < 2; ++nt)
#pragma unroll
        for (int reg = 0; reg < 4; ++reg)
          sh_q[quad * 4 + reg][w * 32 + nt * 16 + nlo] = bf1(silu_f(Cq[nt][reg]));
    }
    __syncthreads();
    f32x4 Cg[2] = {{0,0,0,0},{0,0,0,0}};
    gemm8(sh_q, Wpack + 7 * 16384, w, nlo, quad, Cg);
    float pr[3][4];
#pragma unroll
    for (int d = 0; d < 3; ++d)
#pragma unroll
      for (int reg = 0; reg < 4; ++reg) pr[d][reg] = 0.f;
#pragma unroll
    for (int nt = 0; nt < 2; ++nt)
#pragma unroll
      for (int reg = 0; reg < 4; ++reg) {
        float gv = Cg[nt][reg];
        pr[0][reg] += gv * Cx[nt][reg];
        pr[1][reg] += gv * Cy[nt][reg];
        pr[2][reg] += gv * Cz[nt][reg];
      }
#pragma unroll
    for (int off = 1; off < 16; off <<= 1)
#pragma unroll
      for (int d = 0; d < 3; ++d)
#pragma unroll
        for (int reg = 0; reg < 4; ++reg)
          pr[d][reg] += __shfl_xor(pr[d][reg], off);
    if (nlo == 0 && quad < 2) {
#pragma unroll
      for (int d = 0; d < 3; ++d)
#pragma unroll
        for (int reg = 0; reg < 4; ++reg)
          red[w][quad * 4 + reg][d] = pr[d][reg];
    }
    __syncthreads();
    if (tid < 24) {
      int row = tid / 3, d = tid % 3;
      float s = red[0][row][d] + red[1][row][d] + red[2][row][d] + red[3][row][d];
      out[(size_t)(row0 + row) * 3 + d] = s * fs[0];
    }
  }
}

extern "C" void kernel_launch(void* const* d_in, const int* in_sizes, int n_in,
                              void* d_out, int out_size, void* d_ws, size_t ws_size,
                              hipStream_t stream) {
  const float* pos  = (const float*)d_in[0];
  const int*   z    = (const int*)d_in[1];
  const float* gf   = (const float*)d_in[2];
  const float* emb  = (const float*)d_in[3];
  const float* Wt   = (const float*)d_in[4];
  const float* Wr1  = (const float*)d_in[5];
  const float* Wr2  = (const float*)d_in[6];
  const float* Wupd = (const float*)d_in[7];
  const float* Wmix = (const float*)d_in[8];
  const float* Wg1  = (const float*)d_in[9];
  const float* Wg2  = (const float*)d_in[10];
  const float* fs   = (const float*)d_in[11];
  float* out = (float*)d_out;

  float* ws = (float*)d_ws;
  float* hA = ws;                                         // 2 MB
  unsigned short* apbf = (unsigned short*)(ws + PLANE);   // bf16 planes (0-3 used)
  unsigned short* Wpack = (unsigned short*)(ws + 5 * PLANE);  // 272 KB

  k_init<<<dim3(256), dim3(256), 0, stream>>>(emb, z, gf, Wt, Wr1, Wr2, Wupd,
                                              Wmix, Wg1, Wg2, hA, Wpack);
  k_layer0<<<dim3(BB * 16), dim3(256), 0, stream>>>(pos, hA, apbf, Wpack);
  k_fused<<<dim3(512), dim3(256), 0, stream>>>(pos, hA, apbf, Wpack, fs, out);
}